// Round 11
// baseline (1745864.062 us; speedup 1.0000x reference)
//
#include <hip/hip_runtime.h>
#include <hip/hip_cooperative_groups.h>
#include <cstdint>
#include <cstddef>

namespace cg = cooperative_groups;

typedef _Float16 f16;
typedef _Float16 h8v  __attribute__((ext_vector_type(8)));
typedef float    f32x4 __attribute__((ext_vector_type(4)));

static constexpr int BATCH  = 128;
static constexpr int TSTEPS = 512;
static constexpr int NT     = 256;
static constexpr int SPINMAX = 1 << 22;   // hang->fail conversion bound (~0.5 s)

// fallback (R8 champion) geometry
static constexpr int TB1 = 80, TB2 = 100, TB3 = 32, TB4 = 32;
static constexpr int TNB   = TB1 + TB2 + TB3 + TB4;   // 244
static constexpr int NGRID = TNB + 4;                 // + 4 control blocks (fallback)
static constexpr int NGX   = 256;                     // XCD-team kernel grid

// ---------------- workspace layout (byte offsets) ----------------
// all h tensors batch-major: [slot][b][j]  (f16)
template<int RING> struct WS {
  static constexpr size_t XT  = 0;                                   // f16 [512][128][64]
  static constexpr size_t H1  = XT + 512ull * 128 * 64 * 2;          // f16 [RING][128][640]
  static constexpr size_t H2  = H1 + (size_t)RING * 128 * 640 * 2 + 64;
  static constexpr size_t H3  = H2 + (size_t)RING * 128 * 400 * 2 + 64;
  static constexpr size_t H4  = H3 + (size_t)RING * 128 * 256 * 2 + 64;
  static constexpr size_t PK1 = H4 + (size_t)RING * 128 * 256 * 2 + 64; // f16 packs
  static constexpr size_t PK2 = PK1 + 2560ull * 704  * 2;   // 80*32 == 32*80 rows
  static constexpr size_t PK3 = PK2 + 1600ull * 1056 * 2;   // 100*16 == 25*64 rows
  static constexpr size_t PK4 = PK3 + 1024ull * 672  * 2;
  static constexpr size_t BAR = PK4 + 1024ull * 512  * 2;   // 8 KB sync area
  static constexpr size_t ZERO= BAR + 8192;                          // zeroed h[-1] region
  static constexpr size_t END = ZERO + 163840;
};
// BAR u32 map (xcd kernel): [0..7] slotCnt; [16 + xcd*128 + slot*4 + w] F flags;
// [1040 + xcd*16 + rep*4 + w] team watermarks.  (fallback uses its own layout)

struct KParams {
  const float *x;
  const float *k1, *r1, *b1, *k2, *r2, *b2, *k3, *r3, *b3, *k4, *r4, *b4;
  const float *wd1, *bd1, *wd2, *bd2, *wd3, *bd3, *wd4, *bd4, *wd5, *bd5, *wd6, *bd6;
  float *out;
  char *ws;
};

__device__ __forceinline__ float sigm(float v) { return 1.f / (1.f + expf(-v)); }

// ---- agent-scope (cross-XCD coherent, L3) primitives ----
__device__ __forceinline__ uint64_t c_load8(const void* p) {
  return __hip_atomic_load((const uint64_t*)p, __ATOMIC_RELAXED, __HIP_MEMORY_SCOPE_AGENT);
}
__device__ __forceinline__ void c_store8(void* p, uint64_t v) {
  __hip_atomic_store((uint64_t*)p, v, __ATOMIC_RELAXED, __HIP_MEMORY_SCOPE_AGENT);
}
__device__ __forceinline__ unsigned short c_load2(const void* p) {
  return __hip_atomic_load((const unsigned short*)p, __ATOMIC_RELAXED, __HIP_MEMORY_SCOPE_AGENT);
}
__device__ __forceinline__ unsigned u_load(const unsigned* p) {
  return __hip_atomic_load(p, __ATOMIC_RELAXED, __HIP_MEMORY_SCOPE_AGENT);
}
__device__ __forceinline__ void u_store(unsigned* p, unsigned v) {
  __hip_atomic_store(p, v, __ATOMIC_RELAXED, __HIP_MEMORY_SCOPE_AGENT);
}
__device__ __forceinline__ void acq_fence() {
  __builtin_amdgcn_fence(__ATOMIC_ACQUIRE, "agent");
}

// ---- intra-XCD (L2-coherent) flag ops: sc0 bypasses L1, hits shared L2 ----
__device__ __forceinline__ unsigned f_load(const unsigned* p) {
  unsigned v;
  asm volatile("global_load_dword %0, %1, off sc0\n\ts_waitcnt vmcnt(0)"
               : "=v"(v) : "v"(p) : "memory");
  return v;
}
__device__ __forceinline__ void f_store(unsigned* p, unsigned v) {
  asm volatile("global_store_dword %0, %1, off sc0" :: "v"(p), "v"(v) : "memory");
}
__device__ __forceinline__ int xcc_id() {
  int x;
  asm volatile("s_getreg_b32 %0, hwreg(HW_REG_XCC_ID)" : "=s"(x));
  return x & 7;
}

// ---------------- weight prepack: pack[slot][n][k], n = gate*NJ + jj, zero-padded K ----------------
__device__ void prepack_layer(const float* __restrict__ gk, const float* __restrict__ gr,
                              f16* __restrict__ pack, int DIN, int H, int NJ, int KPAD,
                              int TB, int gtid, int gstr) {
  const int KREAL = DIN + H;
  const int NGC = 4 * NJ;
  const long total = (long)TB * NGC * KPAD;
  for (long e = gtid; e < total; e += gstr) {
    const int  k   = (int)(e % KPAD);
    const long r   = e / KPAD;
    const int  n   = (int)(r % NGC);
    const int  blk = (int)(r / NGC);
    const int  g   = n / NJ, jj = n % NJ;
    const int  j   = blk * NJ + jj;
    float v = 0.f;
    if (k < DIN)        v = gk[(size_t)k * 4 * H + (size_t)g * H + j];
    else if (k < KREAL) v = gr[(size_t)(k - DIN) * 4 * H + (size_t)g * H + j];
    pack[e] = (f16)v;
  }
}

// ---------------- dense head ----------------
__device__ void dense_stage(const float* in, float* outb,
                            const float* __restrict__ w, const float* __restrict__ bias,
                            int din, int dout, bool relu) {
  for (int jc = threadIdx.x; jc < dout; jc += NT) {
    float s = bias[jc];
    for (int d = 0; d < din; ++d) s += in[d] * w[(size_t)d * dout + jc];
    outb[jc] = relu ? fmaxf(s, 0.f) : s;
  }
  __syncthreads();
}

__device__ void dense_head(const KParams& p, const f16* h4row, float* A, float* B, int b) {
  for (int d = threadIdx.x; d < 256; d += NT) {
    union { unsigned short u; f16 h; } cc;
    cc.u = c_load2(h4row + d);
    A[d] = (float)cc.h;
  }
  __syncthreads();
  dense_stage(A, B, p.wd1, p.bd1, 256, 512, true);
  dense_stage(B, A, p.wd2, p.bd2, 512, 256, true);
  dense_stage(A, B, p.wd3, p.bd3, 256, 128, true);
  dense_stage(B, A, p.wd4, p.bd4, 128, 64,  true);
  dense_stage(A, B, p.wd5, p.bd5, 64,  16,  true);
  dense_stage(B, A, p.wd6, p.bd6, 16,  3,   false);
  if (threadIdx.x == 0) {
    float z0 = A[0], z1 = A[1], z2 = A[2];
    float m  = fmaxf(fmaxf(z0, z1), z2);
    float e0 = expf(z0 - m), e1 = expf(z1 - m), e2 = expf(z2 - m);
    float s  = e0 + e1 + e2;
    p.out[b * 3 + 0] = e0 / s;
    p.out[b * 3 + 1] = e1 / s;
    p.out[b * 3 + 2] = e2 / s;
  }
}

// ============================================================================
//                    FALLBACK KERNEL  (R8 champion, verbatim)
// ============================================================================
template<int NBLK>
__device__ void control_role(unsigned* U, int first, int lidx) {
  const int w = threadIdx.x >> 6, lane = threadIdx.x & 63;
  int cand = 1;
  while (cand <= TSTEPS) {
    unsigned v0 = (lane < NBLK)      ? u_load(&U[4 * (first + lane) + w])      : 0xFFFFFFFFu;
    unsigned v1 = (lane + 64 < NBLK) ? u_load(&U[4 * (first + lane + 64) + w]) : 0xFFFFFFFFu;
    unsigned v = v0 < v1 ? v0 : v1;
    if (__all((int)(v >= (unsigned)cand))) {
      if (lane < 16) u_store(&U[1024 + lane * 64 + lidx * 4 + w], (unsigned)cand);
      ++cand;
    }
  }
}

#define FETCH(PP, CC) do { \
  _Pragma("unroll") \
  for (int ii_ = 0; ii_ < C; ++ii_) { \
    const int ks_ = (CC) * C + ii_; \
    if (ks_ < KS) { \
      const int k_ = ks_ * 32 + kg; \
      _Pragma("unroll") \
      for (int m_ = 0; m_ < 2; ++m_) { \
        const int bmv_ = m_ ? bm1 : bm0; \
        uint4 v_ = make_uint4(0u, 0u, 0u, 0u); \
        if constexpr (SEQM) { \
          if (k_ < DIN)        v_ = *(const uint4*)(inP + (size_t)bmv_ * DIN + k_); \
          else if (k_ < KREAL) v_ = *(const uint4*)(inH + (size_t)bmv_ * H + (k_ - DIN)); \
        } else { \
          if (k_ < DIN) { \
            const f16* p_ = inP + (size_t)bmv_ * DIN + k_; \
            if constexpr (SEQIN) { \
              ((uint64_t*)&v_)[0] = *(const uint64_t*)p_; \
              ((uint64_t*)&v_)[1] = *(const uint64_t*)(p_ + 4); \
            } else { \
              ((uint64_t*)&v_)[0] = c_load8(p_); \
              ((uint64_t*)&v_)[1] = c_load8(p_ + 4); \
            } \
          } else if (k_ < KREAL) { \
            const f16* p_ = inH + (size_t)bmv_ * H + (k_ - DIN); \
            ((uint64_t*)&v_)[0] = c_load8(p_); \
            ((uint64_t*)&v_)[1] = c_load8(p_ + 4); \
          } \
        } \
        ab[PP][ii_][m_] = v_; \
      } \
    } \
  } \
} while (0)

#define COMPUTE(PP, CC) do { \
  _Pragma("unroll") \
  for (int ii_ = 0; ii_ < C; ++ii_) { \
    const int ks_ = (CC) * C + ii_; \
    if (ks_ < KS) { \
      const int kb_ = ks_ * 32; \
      h8v bf_[NTI]; \
      _Pragma("unroll") \
      for (int nt_ = 0; nt_ < NTI; ++nt_) \
        bf_[nt_] = *(const h8v*)(wlds + (size_t)(nt_ * 16 + l15) * WROW + kb_ + kg); \
      _Pragma("unroll") \
      for (int m_ = 0; m_ < 2; ++m_) { \
        union { uint4 u; h8v v; } af_; \
        af_.u = ab[PP][ii_][m_]; \
        _Pragma("unroll") \
        for (int nt_ = 0; nt_ < NTI; ++nt_) \
          acc[m_][nt_] = __builtin_amdgcn_mfma_f32_16x16x32_f16(af_.v, bf_[nt_], acc[m_][nt_], 0, 0, 0); \
      } \
    } \
  } \
} while (0)

#define WAITOWN do { \
  bool c_ = (lane != 0) || (rcO >= t); \
  while (!__all((int)c_)) { \
    if (!c_) { rcO = (int)u_load(&relp[LIDX * 4 + w]); c_ = (rcO >= t); } \
  } \
} while (0)

template<int DIN, int H, int NJ, int LIDX, bool SEQIN, int RING>
__device__ void lstm_role(int blk, int bid, const f16* lo_base, f16* ownH,
                          const f16* pack, const float* __restrict__ gbias,
                          const f16* zreg, char* smem, unsigned* U) {
  constexpr bool SEQM = (RING == TSTEPS);
  constexpr int KREAL = DIN + H;
  constexpr int KS    = (KREAL + 31) / 32;
  constexpr int KPAD  = KS * 32;
  constexpr int NGC   = 4 * NJ;
  constexpr int NTI   = NGC / 16;
  constexpr int WROW  = KPAD + 8;
  constexpr int ZROW  = 132;
  constexpr int C     = 6;
  constexpr int NC    = (KS + C - 1) / C;
  constexpr int KSX   = DIN / 32;
  constexpr int CH    = KSX / C;
  static_assert(NC <= 6, "NC");
  static_assert(CH <= NC - 1, "CH");

  const int tid  = threadIdx.x;
  const int w    = tid >> 6, lane = tid & 63;
  const int l15  = lane & 15;
  const int kg   = (lane >> 4) * 8;
  const int bm0  = w * 32 + l15;
  const int bm1  = bm0 + 16;

  f16*   wlds = (f16*)smem;
  float* z    = (float*)(smem + (size_t)NGC * WROW * 2);

  {
    const f16* src = pack + (size_t)blk * NGC * KPAD;
    constexpr int RU = KPAD / 8;
    for (int u = tid; u < NGC * RU; u += NT) {
      const int n = u / RU, k8 = u % RU;
      *(uint4*)(wlds + (size_t)n * WROW + k8 * 8) =
          *(const uint4*)(src + (size_t)n * KPAD + k8 * 8);
    }
  }
  __syncthreads();

  constexpr int JW = NJ / 4;
  const int be  = 32 * w + lane / JW;
  const int jg  = lane % JW;
  const bool epi = (lane < 32 * JW);
  const int j0  = blk * NJ + jg * 4;
  f32x4 bias4[4] = {};
  if (epi) {
    #pragma unroll
    for (int g = 0; g < 4; ++g) bias4[g] = *(const f32x4*)(gbias + (size_t)g * H + j0);
  }
  float cst[4] = {0.f, 0.f, 0.f, 0.f};

  const unsigned* relp = &U[1024 + (bid & 15) * 64];
  int rcI = 0, rcO = 0, rcD = 0;
  (void)rcI; (void)rcD;

  for (int t = 0; t < TSTEPS; ++t) {
    {
      bool c = true;
      if constexpr (LIDX > 0) { if (lane == 0) c = (rcI >= t + 1); }
      if constexpr (CH == 0)  { if (lane == 1) c = (rcO >= t); }
      if constexpr (!SEQM && LIDX < 3) { if (lane == 2) c = (rcD >= t - (RING - 1)); }
      while (!__all((int)c)) {
        if (!c) {
          if constexpr (LIDX > 0) {
            if (lane == 0) { rcI = (int)u_load(&relp[(LIDX - 1) * 4 + w]); c = (rcI >= t + 1); }
          }
          if constexpr (CH == 0) {
            if (lane == 1) { rcO = (int)u_load(&relp[LIDX * 4 + w]); c = (rcO >= t); }
          }
          if constexpr (!SEQM && LIDX < 3) {
            if (lane == 2) { rcD = (int)u_load(&relp[(LIDX + 1) * 4 + w]); c = (rcD >= t - (RING - 1)); }
          }
        }
      }
    }

    const f16* inP = SEQIN ? lo_base + (size_t)t * DIN * BATCH
                           : lo_base + (size_t)(t & (RING - 1)) * DIN * BATCH;
    const f16* inH = (t == 0) ? zreg
                              : ownH + (size_t)((t - 1) & (RING - 1)) * H * BATCH;

    f32x4 acc[2][NTI];
    {
      const f32x4 zz = {0.f, 0.f, 0.f, 0.f};
      #pragma unroll
      for (int m_ = 0; m_ < 2; ++m_)
        #pragma unroll
        for (int nt_ = 0; nt_ < NTI; ++nt_) acc[m_][nt_] = zz;
    }

    uint4 ab[3][C][2];

    FETCH(0, 0);
    if constexpr (NC > 1) { if constexpr (CH == 1) WAITOWN; FETCH(1, 1); }
    if constexpr (NC > 2) { if constexpr (CH == 2) WAITOWN; FETCH(2, 2); }
    COMPUTE(0, 0);
    if constexpr (NC > 1) { if constexpr (NC > 3) { if constexpr (CH == 3) WAITOWN; FETCH(0, 3); } COMPUTE(1, 1); }
    if constexpr (NC > 2) { if constexpr (NC > 4) { if constexpr (CH == 4) WAITOWN; FETCH(1, 4); } COMPUTE(2, 2); }
    if constexpr (NC > 3) { if constexpr (NC > 5) { if constexpr (CH == 5) WAITOWN; FETCH(2, 5); } COMPUTE(0, 3); }
    if constexpr (NC > 4) COMPUTE(1, 4);
    if constexpr (NC > 5) COMPUTE(2, 5);

    #pragma unroll
    for (int m_ = 0; m_ < 2; ++m_)
      #pragma unroll
      for (int nt_ = 0; nt_ < NTI; ++nt_)
        *(f32x4*)(z + (size_t)(nt_ * 16 + l15) * ZROW + w * 32 + m_ * 16 + (lane >> 4) * 4) =
            acc[m_][nt_];

    if (epi) {
      float vi[4], vf[4], vg[4], vo[4];
      #pragma unroll
      for (int q = 0; q < 4; ++q) {
        const int nn = jg * 4 + q;
        vi[q] = z[(size_t)(0 * NJ + nn) * ZROW + be];
        vf[q] = z[(size_t)(1 * NJ + nn) * ZROW + be];
        vg[q] = z[(size_t)(2 * NJ + nn) * ZROW + be];
        vo[q] = z[(size_t)(3 * NJ + nn) * ZROW + be];
      }
      union { f16 h[4]; uint64_t u; } o;
      #pragma unroll
      for (int q = 0; q < 4; ++q) {
        const float ig = sigm(vi[q] + bias4[0][q]);
        const float fg = sigm(vf[q] + bias4[1][q]);
        const float gg = tanhf(vg[q] + bias4[2][q]);
        const float og = sigm(vo[q] + bias4[3][q]);
        cst[q] = fg * cst[q] + ig * gg;
        o.h[q] = (f16)(og * tanhf(cst[q]));
      }
      c_store8(ownH + (size_t)(t & (RING - 1)) * H * BATCH + (size_t)be * H + j0, o.u);
    }
    asm volatile("s_waitcnt vmcnt(0)" ::: "memory");
    if (lane == 0) u_store(&U[4 * bid + w], (unsigned)(t + 1));
  }
}
#undef FETCH
#undef COMPUTE
#undef WAITOWN

constexpr size_t cmax(size_t a, size_t b) { return a > b ? a : b; }
constexpr size_t wlz(int NGC, int KPAD) {
  return (size_t)NGC * (KPAD + 8) * 2 + (size_t)NGC * 132 * 4;
}
static constexpr size_t SMEM_FB =
    cmax(cmax(wlz(32, 704), wlz(16, 1056)),
         cmax(cmax(wlz(32, 672), wlz(32, 512)), (size_t)4096));
static_assert(SMEM_FB <= 65536, "LDS fb");

template<int RING>
__global__ __launch_bounds__(NT, 1) void fused_fb(KParams p) {
  using L = WS<RING>;
  cg::grid_group grid = cg::this_grid();
  __shared__ __attribute__((aligned(16))) char smem[SMEM_FB];

  char* ws = p.ws;
  unsigned* U = (unsigned*)(ws + L::BAR);
  const f16* zreg = (const f16*)(ws + L::ZERO);
  const int tid  = threadIdx.x;
  const int bid  = blockIdx.x;
  const int gtid = bid * NT + tid;
  const int gstr = NGRID * NT;

  prepack_layer(p.k1, p.r1, (f16*)(ws + L::PK1), 64,  640, 8, 704,  TB1, gtid, gstr);
  prepack_layer(p.k2, p.r2, (f16*)(ws + L::PK2), 640, 400, 4, 1056, TB2, gtid, gstr);
  prepack_layer(p.k3, p.r3, (f16*)(ws + L::PK3), 400, 256, 8, 672,  TB3, gtid, gstr);
  prepack_layer(p.k4, p.r4, (f16*)(ws + L::PK4), 256, 256, 8, 512,  TB4, gtid, gstr);
  {
    f16* xT = (f16*)(ws + L::XT);
    const long total = (long)TSTEPS * BATCH * 8;
    for (long u = gtid; u < total; u += gstr) {
      const int  d8 = (int)(u & 7);
      const long r  = u >> 3;
      const int  b  = (int)(r & (BATCH - 1));
      const int  t  = (int)(r >> 7);
      const float* src = p.x + ((size_t)b * TSTEPS + t) * 64 + d8 * 8;
      const float4 v0 = *(const float4*)src;
      const float4 v1 = *(const float4*)(src + 4);
      h8v o;
      o[0] = (f16)v0.x; o[1] = (f16)v0.y; o[2] = (f16)v0.z; o[3] = (f16)v0.w;
      o[4] = (f16)v1.x; o[5] = (f16)v1.y; o[6] = (f16)v1.z; o[7] = (f16)v1.w;
      *(h8v*)(xT + ((size_t)t * BATCH + b) * 64 + d8 * 8) = o;
    }
  }

  grid.sync();
  acq_fence();

  constexpr int TRB2 = TB1, TRB3 = TB1 + TB2, TRB4 = TB1 + TB2 + TB3;
  if (bid >= TNB) {
    const int l = bid - TNB;
    if (l == 0)      control_role<TB1>(U, 0,    0);
    else if (l == 1) control_role<TB2>(U, TRB2, 1);
    else if (l == 2) control_role<TB3>(U, TRB3, 2);
    else             control_role<TB4>(U, TRB4, 3);
  } else if (bid < TRB2) {
    lstm_role< 64, 640, 8, 0, true , RING>(bid, bid, (const f16*)(ws + L::XT),
        (f16*)(ws + L::H1), (const f16*)(ws + L::PK1), p.b1, zreg, smem, U);
  } else if (bid < TRB3) {
    lstm_role<640, 400, 4, 1, false, RING>(bid - TRB2, bid, (const f16*)(ws + L::H1),
        (f16*)(ws + L::H2), (const f16*)(ws + L::PK2), p.b2, zreg, smem, U);
  } else if (bid < TRB4) {
    lstm_role<400, 256, 8, 2, false, RING>(bid - TRB3, bid, (const f16*)(ws + L::H2),
        (f16*)(ws + L::H3), (const f16*)(ws + L::PK3), p.b3, zreg, smem, U);
  } else {
    lstm_role<256, 256, 8, 3, false, RING>(bid - TRB4, bid, (const f16*)(ws + L::H3),
        (f16*)(ws + L::H4), (const f16*)(ws + L::PK4), p.b4, zreg, smem, U);
  }

  if (bid < BATCH) {
    {
      int cond = 1;
      if (tid < 4 * TB4) cond = ((int)u_load(&U[4 * (TRB4 + (tid >> 2)) + (tid & 3)]) >= TSTEPS);
      while (!__syncthreads_and(cond)) {
        if (!cond) cond = ((int)u_load(&U[4 * (TRB4 + (tid >> 2)) + (tid & 3)]) >= TSTEPS);
      }
    }
    const f16* h4 = (const f16*)(ws + L::H4)
                  + (size_t)((TSTEPS - 1) & (RING - 1)) * 256 * BATCH + (size_t)bid * 256;
    dense_head(p, h4, (float*)smem, (float*)smem + 512, bid);
  }
}

// ============================================================================
//                XCD-TEAM KERNEL  (intra-L2 recurrence sync, hang-proofed)
// ============================================================================
// teams: xcd -> layer = xcd>>1, half = xcd&1; 1 block/CU forced by 125 KB LDS.
static constexpr size_t SMEM_X = 125440;   // L1 team: 80*648*2 + 80*68*4

#define TFETCH(PP, CC) do { \
  _Pragma("unroll") \
  for (int ii_ = 0; ii_ < C; ++ii_) { \
    const int ks_ = (CC) * C + ii_; \
    if (ks_ < KS) { \
      const int k_ = ks_ * 32 + kg; \
      uint4 v_ = make_uint4(0u, 0u, 0u, 0u); \
      if (k_ < DIN)        v_ = *(const uint4*)(inP + (size_t)bm * DIN + k_); \
      else if (k_ < KREAL) v_ = *(const uint4*)(inH + (size_t)bm * H + (k_ - DIN)); \
      ab[PP][ii_] = v_; \
    } \
  } \
} while (0)

#define TCOMPUTE(PP, CC) do { \
  _Pragma("unroll") \
  for (int ii_ = 0; ii_ < C; ++ii_) { \
    const int ks_ = (CC) * C + ii_; \
    if (ks_ < KS) { \
      const int kb_ = ks_ * 32; \
      h8v bf_[NTI]; \
      _Pragma("unroll") \
      for (int nt_ = 0; nt_ < NTI; ++nt_) { \
        const int n_ = nt_ * 16 + l15; \
        if (kb_ >= LDSK0 && kb_ < LDSK1) \
          bf_[nt_] = *(const h8v*)(wlds + (size_t)n_ * WROW + (kb_ - LDSK0) + kg); \
        else \
          bf_[nt_] = *(const h8v*)(gpk + (size_t)n_ * KPAD + kb_ + kg); \
      } \
      union { uint4 u; h8v v; } af_; af_.u = ab[PP][ii_]; \
      _Pragma("unroll") \
      for (int nt_ = 0; nt_ < NTI; ++nt_) \
        acc[nt_] = __builtin_amdgcn_mfma_f32_16x16x32_f16(af_.v, bf_[nt_], acc[nt_], 0, 0, 0); \
    } \
  } \
} while (0)

// own-peer wait (sc0, intra-XCD), timeout-guarded; slot0 watermark publish (sc1)
#define TWAITOWN do { \
  if (!dead) { \
    int grd_ = 0; \
    bool c_ = (lane >= TS) || (rcO >= t); \
    while (!__all((int)c_)) { \
      if (++grd_ > SPINMAX) { dead = 1; break; } \
      if (!c_) { \
        rcO = (int)f_load(Fo + lane * 4 + w); c_ = (rcO >= t); \
        if (!c_) __builtin_amdgcn_s_sleep(1); \
      } \
    } \
  } \
  if (slot == 0 && lane == 0) { \
    _Pragma("unroll") \
    for (int rp_ = 0; rp_ < 4; ++rp_) u_store(WMo + rp_ * 4 + w, (unsigned)t); \
  } \
} while (0)

template<int DIN, int H, int NJL, int TS, int LIDX, int LDSK0, int LDSK1>
__device__ void team_role(int slot, int xcd, int half,
                          const f16* lo_base, f16* ownH, const f16* pack,
                          const float* __restrict__ gbias, const f16* zreg,
                          char* smem, unsigned* Bu) {
  constexpr int KREAL = DIN + H;
  constexpr int KPAD  = ((KREAL + 31) / 32) * 32;
  constexpr int KS    = KPAD / 32;
  constexpr int NGC   = 4 * NJL;
  constexpr int NTI   = NGC / 16;
  constexpr int LKW   = LDSK1 - LDSK0;
  constexpr int WROW  = LKW + 8;
  constexpr int ZROW  = 68;
  constexpr int C     = 6;
  constexpr int NC    = (KS + C - 1) / C;
  constexpr int CH    = (DIN / 32) / C;
  static_assert(NC <= 6 && CH <= NC - 1, "geom");
  static_assert((size_t)NGC * WROW * 2 + (size_t)NGC * ZROW * 4 <= SMEM_X, "lds");

  const int tid = threadIdx.x, w = tid >> 6, lane = tid & 63;
  const int l15 = lane & 15, kg = (lane >> 4) * 8;
  const int bm  = half * 64 + 16 * w + l15;     // global batch row (A operand)

  f16*   wlds = (f16*)smem;
  float* z    = (float*)(smem + (size_t)NGC * WROW * 2);
  const f16* gpk = pack + (size_t)slot * NGC * KPAD;

  // LDS-resident weight stripe (k in [LDSK0, LDSK1))
  {
    constexpr int RU = LKW / 8;
    for (int u = tid; u < NGC * RU; u += NT) {
      const int n = u / RU, k8 = u % RU;
      *(uint4*)(wlds + (size_t)n * WROW + k8 * 8) =
          *(const uint4*)(gpk + (size_t)n * KPAD + LDSK0 + k8 * 8);
    }
  }
  __syncthreads();

  // epilogue items: per wave 16 batches x JW j-groups
  constexpr int JW    = NJL / 4;
  constexpr int NITEM = 16 * JW;
  constexpr int NIT   = (NITEM + 63) / 64;
  float cst[NIT][4] = {};
  f32x4 bias4[NIT][4];
  #pragma unroll
  for (int ii = 0; ii < NIT; ++ii) {
    const int it = ii * 64 + lane;
    if (it < NITEM) {
      const int g4 = it % JW;
      const int j0 = slot * NJL + g4 * 4;
      #pragma unroll
      for (int g = 0; g < 4; ++g) bias4[ii][g] = *(const f32x4*)(gbias + (size_t)g * H + j0);
    }
  }

  unsigned* Fo  = Bu + 16 + xcd * 128;              // + slot*4 + w
  unsigned* WMo = Bu + 1040 + xcd * 16;             // + rep*4 + w
  const unsigned* WMp = Bu + 1040 + (xcd - 2) * 16; // prev layer, same half
  const int rep = slot & 3;
  int rcP = 0, rcO = 0;
  int dead = 0;

  for (int t = 0; t < TSTEPS; ++t) {
    // ---- top wait: prev-layer watermark (sc1); own peers if CH==0; guarded ----
    if (!dead) {
      int grd = 0;
      bool c = true;
      if constexpr (LIDX > 0) { if (lane == 0) c = (rcP >= t + 1); }
      if constexpr (CH == 0)  { if (lane < TS) c = c && (rcO >= t); }
      while (!__all((int)c)) {
        if (++grd > SPINMAX) { dead = 1; break; }
        if (!c) {
          if constexpr (LIDX > 0)
            if (lane == 0 && rcP < t + 1) rcP = (int)u_load(WMp + rep * 4 + w);
          if constexpr (CH == 0)
            if (lane < TS && rcO < t) rcO = (int)f_load(Fo + lane * 4 + w);
          c = true;
          if constexpr (LIDX > 0) { if (lane == 0) c = (rcP >= t + 1); }
          if constexpr (CH == 0)  { if (lane < TS) c = c && (rcO >= t); }
          if (!c) __builtin_amdgcn_s_sleep(1);
        }
      }
    }
    if constexpr (CH == 0) {
      if (slot == 0 && lane == 0) {
        #pragma unroll
        for (int rp = 0; rp < 4; ++rp) u_store(WMo + rp * 4 + w, (unsigned)t);
      }
    }

    const f16* inP = lo_base + (size_t)t * DIN * BATCH;
    const f16* inH = (t == 0) ? zreg : ownH + (size_t)(t - 1) * H * BATCH;

    f32x4 acc[NTI];
    {
      const f32x4 zz = {0.f, 0.f, 0.f, 0.f};
      #pragma unroll
      for (int nt_ = 0; nt_ < NTI; ++nt_) acc[nt_] = zz;
    }
    uint4 ab[3][C];

    TFETCH(0, 0);
    if constexpr (NC > 1) { if constexpr (CH == 1) TWAITOWN; TFETCH(1, 1); }
    if constexpr (NC > 2) { if constexpr (CH == 2) TWAITOWN; TFETCH(2, 2); }
    TCOMPUTE(0, 0);
    if constexpr (NC > 1) { if constexpr (NC > 3) { if constexpr (CH == 3) TWAITOWN; TFETCH(0, 3); } TCOMPUTE(1, 1); }
    if constexpr (NC > 2) { if constexpr (NC > 4) { if constexpr (CH == 4) TWAITOWN; TFETCH(1, 4); } TCOMPUTE(2, 2); }
    if constexpr (NC > 3) { if constexpr (NC > 5) { if constexpr (CH == 5) TWAITOWN; TFETCH(2, 5); } TCOMPUTE(0, 3); }
    if constexpr (NC > 4) TCOMPUTE(1, 4);
    if constexpr (NC > 5) TCOMPUTE(2, 5);

    // ---- D -> z[gatecol][teambatch] (wave-local columns, no barrier) ----
    #pragma unroll
    for (int nt_ = 0; nt_ < NTI; ++nt_)
      *(f32x4*)(z + (size_t)(nt_ * 16 + l15) * ZROW + 16 * w + (lane >> 4) * 4) = acc[nt_];

    // ---- epilogue: gates, state, coalesced 8B sc1 h store ----
    #pragma unroll
    for (int ii = 0; ii < NIT; ++ii) {
      const int it = ii * 64 + lane;
      if (it < NITEM) {
        const int bb = it / JW, g4 = it % JW;
        const int beL = 16 * w + bb;
        const int j0  = slot * NJL + g4 * 4;
        union { f16 h[4]; uint64_t u; } o;
        #pragma unroll
        for (int q = 0; q < 4; ++q) {
          const int nn = g4 * 4 + q;
          const float vi = z[(size_t)(0 * NJL + nn) * ZROW + beL];
          const float vf = z[(size_t)(1 * NJL + nn) * ZROW + beL];
          const float vg = z[(size_t)(2 * NJL + nn) * ZROW + beL];
          const float vo = z[(size_t)(3 * NJL + nn) * ZROW + beL];
          const float ig = sigm(vi + bias4[ii][0][q]);
          const float fg = sigm(vf + bias4[ii][1][q]);
          const float gg = tanhf(vg + bias4[ii][2][q]);
          const float og = sigm(vo + bias4[ii][3][q]);
          cst[ii][q] = fg * cst[ii][q] + ig * gg;
          o.h[q] = (f16)(og * tanhf(cst[ii][q]));
        }
        c_store8(ownH + (size_t)t * H * BATCH + (size_t)(half * 64 + beL) * H + j0, o.u);
      }
    }
    asm volatile("s_waitcnt vmcnt(0)" ::: "memory");   // drain sc1 h-stores
    if (lane == 0) f_store(Fo + slot * 4 + w, (unsigned)(t + 1));  // sc0 intra-XCD flag
  }

  // ---- final watermark: all peers done 512 -> WM = TSTEPS (guarded) ----
  if (slot == 0) {
    int grd = 0;
    bool c = (lane >= TS);
    int rcF = 0;
    while (!__all((int)c)) {
      if (++grd > SPINMAX) break;
      if (!c) {
        rcF = (int)f_load(Fo + lane * 4 + w);
        c = (rcF >= TSTEPS);
        if (!c) __builtin_amdgcn_s_sleep(1);
      }
    }
    if (lane == 0) {
      #pragma unroll
      for (int rp = 0; rp < 4; ++rp) u_store(WMo + rp * 4 + w, (unsigned)TSTEPS);
    }
  }
}
#undef TFETCH
#undef TCOMPUTE
#undef TWAITOWN

__global__ __launch_bounds__(NT, 1) void fused_xcd(KParams p) {
  using L = WS<TSTEPS>;
  cg::grid_group grid = cg::this_grid();
  __shared__ __attribute__((aligned(16))) char smem[SMEM_X];
  __shared__ int sxcd, sslot;

  char* ws = p.ws;
  unsigned* Bu = (unsigned*)(ws + L::BAR);
  const f16* zreg = (const f16*)(ws + L::ZERO);
  const int tid = threadIdx.x;
  const int bid = blockIdx.x;
  const int gtid = bid * NT + tid;
  const int gstr = NGX * NT;

  // ---- role probe: actual XCD + team slot (placement-agnostic correctness) ----
  if (tid == 0) {
    const int x = xcc_id();
    sxcd = x;
    sslot = (int)__hip_atomic_fetch_add(&Bu[x], 1u, __ATOMIC_RELAXED, __HIP_MEMORY_SCOPE_AGENT);
  }

  // ---- phase 0: prepack (team geometry) + x transpose ----
  prepack_layer(p.k1, p.r1, (f16*)(ws + L::PK1), 64,  640, 20, 704,  32, gtid, gstr);
  prepack_layer(p.k2, p.r2, (f16*)(ws + L::PK2), 640, 400, 16, 1056, 25, gtid, gstr);
  prepack_layer(p.k3, p.r3, (f16*)(ws + L::PK3), 400, 256, 8,  672,  32, gtid, gstr);
  prepack_layer(p.k4, p.r4, (f16*)(ws + L::PK4), 256, 256, 8,  512,  32, gtid, gstr);
  {
    f16* xT = (f16*)(ws + L::XT);
    const long total = (long)TSTEPS * BATCH * 8;
    for (long u = gtid; u < total; u += gstr) {
      const int  d8 = (int)(u & 7);
      const long r  = u >> 3;
      const int  b  = (int)(r & (BATCH - 1));
      const int  t  = (int)(r >> 7);
      const float* src = p.x + ((size_t)b * TSTEPS + t) * 64 + d8 * 8;
      const float4 v0 = *(const float4*)src;
      const float4 v1 = *(const float4*)(src + 4);
      h8v o;
      o[0] = (f16)v0.x; o[1] = (f16)v0.y; o[2] = (f16)v0.z; o[3] = (f16)v0.w;
      o[4] = (f16)v1.x; o[5] = (f16)v1.y; o[6] = (f16)v1.z; o[7] = (f16)v1.w;
      *(h8v*)(xT + ((size_t)t * BATCH + b) * 64 + d8 * 8) = o;
    }
  }

  grid.sync();
  acq_fence();
  __syncthreads();

  const int xcd = sxcd, slot = sslot;
  const int layer = xcd >> 1, half = xcd & 1;

  // ---- phase 1: XCD-team LSTM scan ----
  if (layer == 0) {
    if (slot < 32) team_role< 64, 640, 20, 32, 0,  64,  704>(slot, xcd, half,
        (const f16*)(ws + L::XT), (f16*)(ws + L::H1), (const f16*)(ws + L::PK1),
        p.b1, zreg, smem, Bu);
  } else if (layer == 1) {
    if (slot < 25) team_role<640, 400, 16, 25, 1,   0,  640>(slot, xcd, half,
        (const f16*)(ws + L::H1), (f16*)(ws + L::H2), (const f16*)(ws + L::PK2),
        p.b2, zreg, smem, Bu);
  } else if (layer == 2) {
    if (slot < 32) team_role<400, 256,  8, 32, 2,   0,  672>(slot, xcd, half,
        (const f16*)(ws + L::H2), (f16*)(ws + L::H3), (const f16*)(ws + L::PK3),
        p.b3, zreg, smem, Bu);
  } else {
    if (slot < 32) team_role<256, 256,  8, 32, 3,   0,  512>(slot, xcd, half,
        (const f16*)(ws + L::H3), (f16*)(ws + L::H4), (const f16*)(ws + L::PK4),
        p.b4, zreg, smem, Bu);
  }

  // ---- phase 2: dense head (guarded wait) ----
  if (bid < BATCH) {
    const int hb = (bid >= 64) ? 1 : 0;
    {
      int grd = 0;
      int cond = 1;
      if (tid < 4)
        cond = ((int)u_load(Bu + 1040 + (6 + hb) * 16 + (bid & 3) * 4 + tid) >= TSTEPS);
      while (!__syncthreads_and(cond)) {
        if (++grd > SPINMAX) break;
        if (!cond) {
          cond = ((int)u_load(Bu + 1040 + (6 + hb) * 16 + (bid & 3) * 4 + tid) >= TSTEPS);
          if (!cond) __builtin_amdgcn_s_sleep(1);
        }
      }
    }
    const f16* h4 = (const f16*)(ws + L::H4)
                  + (size_t)(TSTEPS - 1) * 256 * BATCH + (size_t)bid * 256;
    dense_head(p, h4, (float*)smem, (float*)smem + 512, bid);
  }
}

// ---------------- launch ----------------
extern "C" void kernel_launch(void* const* d_in, const int* in_sizes, int n_in,
                              void* d_out, int out_size, void* d_ws, size_t ws_size,
                              hipStream_t stream) {
  (void)in_sizes; (void)n_in; (void)out_size;
  KParams prm;
  prm.x  = (const float*)d_in[0];
  prm.k1 = (const float*)d_in[1];  prm.r1 = (const float*)d_in[2];  prm.b1 = (const float*)d_in[3];
  prm.k2 = (const float*)d_in[4];  prm.r2 = (const float*)d_in[5];  prm.b2 = (const float*)d_in[6];
  prm.k3 = (const float*)d_in[7];  prm.r3 = (const float*)d_in[8];  prm.b3 = (const float*)d_in[9];
  prm.k4 = (const float*)d_in[10]; prm.r4 = (const float*)d_in[11]; prm.b4 = (const float*)d_in[12];
  prm.wd1 = (const float*)d_in[13]; prm.bd1 = (const float*)d_in[14];
  prm.wd2 = (const float*)d_in[15]; prm.bd2 = (const float*)d_in[16];
  prm.wd3 = (const float*)d_in[17]; prm.bd3 = (const float*)d_in[18];
  prm.wd4 = (const float*)d_in[19]; prm.bd4 = (const float*)d_in[20];
  prm.wd5 = (const float*)d_in[21]; prm.bd5 = (const float*)d_in[22];
  prm.wd6 = (const float*)d_in[23]; prm.bd6 = (const float*)d_in[24];
  prm.out = (float*)d_out;
  prm.ws  = (char*)d_ws;

  const bool big = ws_size >= WS<TSTEPS>::END;
  const size_t bar_off = big ? WS<TSTEPS>::BAR : WS<4>::BAR;
  hipMemsetAsync((char*)d_ws + bar_off, 0, 8192 + 163840, stream);

  void* args[] = { &prm };
  if (big) {
    // XCD-team kernel needs 1 block/CU (forced by 125 KB LDS) and 256 co-resident blocks
    int maxb = 0;
    hipOccupancyMaxActiveBlocksPerMultiprocessor(&maxb, (const void*)fused_xcd, NT, 0);
    hipError_t e = hipErrorUnknown;
    if (maxb >= 1) {
      e = hipLaunchCooperativeKernel((void*)fused_xcd, dim3(NGX), dim3(NT), args, 0, stream);
    }
    if (e != hipSuccess) {
      hipLaunchCooperativeKernel((void*)fused_fb<TSTEPS>, dim3(NGRID), dim3(NT), args, 0, stream);
    }
  } else {
    hipLaunchCooperativeKernel((void*)fused_fb<4>, dim3(NGRID), dim3(NT), args, 0, stream);
  }
}

// Round 12
// 551112.305 us; speedup vs baseline: 3.1679x; 3.1679x over previous
//
#include <hip/hip_runtime.h>
#include <hip/hip_cooperative_groups.h>
#include <cstdint>
#include <cstddef>

namespace cg = cooperative_groups;

typedef _Float16 f16;
typedef _Float16 h8v  __attribute__((ext_vector_type(8)));
typedef float    f32x4 __attribute__((ext_vector_type(4)));

static constexpr int BATCH  = 128;
static constexpr int TSTEPS = 512;
static constexpr int NT     = 256;
static constexpr int SPINMAX = 1 << 20;   // hang->fail conversion bound (~0.13 s)

// fallback (R8 champion) geometry
static constexpr int TB1 = 80, TB2 = 100, TB3 = 32, TB4 = 32;
static constexpr int TNB   = TB1 + TB2 + TB3 + TB4;   // 244
static constexpr int NGRID = TNB + 4;                 // + 4 control blocks (fallback)
static constexpr int NGX   = 256;                     // XCD-team kernel grid

// ---------------- workspace layout (byte offsets) ----------------
// all h tensors batch-major: [slot][b][j]  (f16)
template<int RING> struct WS {
  static constexpr size_t XT  = 0;                                   // f16 [512][128][64]
  static constexpr size_t H1  = XT + 512ull * 128 * 64 * 2;          // f16 [RING][128][640]
  static constexpr size_t H2  = H1 + (size_t)RING * 128 * 640 * 2 + 64;
  static constexpr size_t H3  = H2 + (size_t)RING * 128 * 400 * 2 + 64;
  static constexpr size_t H4  = H3 + (size_t)RING * 128 * 256 * 2 + 64;
  static constexpr size_t PK1 = H4 + (size_t)RING * 128 * 256 * 2 + 64; // f16 packs
  static constexpr size_t PK2 = PK1 + 2560ull * 704  * 2;   // 80*32 == 32*80 rows
  static constexpr size_t PK3 = PK2 + 1600ull * 1056 * 2;   // 100*16 == 25*64 rows
  static constexpr size_t PK4 = PK3 + 1024ull * 672  * 2;
  static constexpr size_t BAR = PK4 + 1024ull * 512  * 2;   // 8 KB sync area
  static constexpr size_t ZERO= BAR + 8192;                          // zeroed h[-1] region
  static constexpr size_t END = ZERO + 163840;
};
// BAR u32 map (xcd kernel): [0..7] slotCnt; [16 + xcd*128 + slot*4 + w] F flags;
// [1040 + xcd*16 + rep*4 + w] team watermarks.  (fallback uses its own layout)

struct KParams {
  const float *x;
  const float *k1, *r1, *b1, *k2, *r2, *b2, *k3, *r3, *b3, *k4, *r4, *b4;
  const float *wd1, *bd1, *wd2, *bd2, *wd3, *bd3, *wd4, *bd4, *wd5, *bd5, *wd6, *bd6;
  float *out;
  char *ws;
};

__device__ __forceinline__ float sigm(float v) { return 1.f / (1.f + expf(-v)); }

// ---- agent-scope (cross-XCD coherent, L3) primitives ----
__device__ __forceinline__ uint64_t c_load8(const void* p) {
  return __hip_atomic_load((const uint64_t*)p, __ATOMIC_RELAXED, __HIP_MEMORY_SCOPE_AGENT);
}
__device__ __forceinline__ void c_store8(void* p, uint64_t v) {
  __hip_atomic_store((uint64_t*)p, v, __ATOMIC_RELAXED, __HIP_MEMORY_SCOPE_AGENT);
}
__device__ __forceinline__ unsigned short c_load2(const void* p) {
  return __hip_atomic_load((const unsigned short*)p, __ATOMIC_RELAXED, __HIP_MEMORY_SCOPE_AGENT);
}
__device__ __forceinline__ unsigned u_load(const unsigned* p) {
  return __hip_atomic_load(p, __ATOMIC_RELAXED, __HIP_MEMORY_SCOPE_AGENT);
}
__device__ __forceinline__ void u_store(unsigned* p, unsigned v) {
  __hip_atomic_store(p, v, __ATOMIC_RELAXED, __HIP_MEMORY_SCOPE_AGENT);
}
__device__ __forceinline__ void acq_fence() {
  __builtin_amdgcn_fence(__ATOMIC_ACQUIRE, "agent");
}

// ---- intra-XCD flag ops, REPAIRED (R11 post-mortem):
// sc0 LOAD polls were served from the polling CU's own (incoherent) L1 ->
// stale-spin -> timeout. Fix: read the flag with a workgroup-scope atomic
// fetch-add(0) — global atomics execute at the XCD-shared L2 atomic units,
// so the poll observes peer stores at L2 latency without touching L3.
__device__ __forceinline__ unsigned f_load(const unsigned* p) {
  return __hip_atomic_fetch_add((unsigned*)p, 0u, __ATOMIC_RELAXED,
                                __HIP_MEMORY_SCOPE_WORKGROUP);
}
__device__ __forceinline__ void f_store(unsigned* p, unsigned v) {
  __hip_atomic_store(p, v, __ATOMIC_RELAXED, __HIP_MEMORY_SCOPE_WORKGROUP);
}
__device__ __forceinline__ int xcc_id() {
  int x;
  asm volatile("s_getreg_b32 %0, hwreg(HW_REG_XCC_ID)" : "=s"(x));
  return x & 7;
}

// ---------------- weight prepack: pack[slot][n][k], n = gate*NJ + jj, zero-padded K ----------------
__device__ void prepack_layer(const float* __restrict__ gk, const float* __restrict__ gr,
                              f16* __restrict__ pack, int DIN, int H, int NJ, int KPAD,
                              int TB, int gtid, int gstr) {
  const int KREAL = DIN + H;
  const int NGC = 4 * NJ;
  const long total = (long)TB * NGC * KPAD;
  for (long e = gtid; e < total; e += gstr) {
    const int  k   = (int)(e % KPAD);
    const long r   = e / KPAD;
    const int  n   = (int)(r % NGC);
    const int  blk = (int)(r / NGC);
    const int  g   = n / NJ, jj = n % NJ;
    const int  j   = blk * NJ + jj;
    float v = 0.f;
    if (k < DIN)        v = gk[(size_t)k * 4 * H + (size_t)g * H + j];
    else if (k < KREAL) v = gr[(size_t)(k - DIN) * 4 * H + (size_t)g * H + j];
    pack[e] = (f16)v;
  }
}

// ---------------- dense head ----------------
__device__ void dense_stage(const float* in, float* outb,
                            const float* __restrict__ w, const float* __restrict__ bias,
                            int din, int dout, bool relu) {
  for (int jc = threadIdx.x; jc < dout; jc += NT) {
    float s = bias[jc];
    for (int d = 0; d < din; ++d) s += in[d] * w[(size_t)d * dout + jc];
    outb[jc] = relu ? fmaxf(s, 0.f) : s;
  }
  __syncthreads();
}

__device__ void dense_head(const KParams& p, const f16* h4row, float* A, float* B, int b) {
  for (int d = threadIdx.x; d < 256; d += NT) {
    union { unsigned short u; f16 h; } cc;
    cc.u = c_load2(h4row + d);
    A[d] = (float)cc.h;
  }
  __syncthreads();
  dense_stage(A, B, p.wd1, p.bd1, 256, 512, true);
  dense_stage(B, A, p.wd2, p.bd2, 512, 256, true);
  dense_stage(A, B, p.wd3, p.bd3, 256, 128, true);
  dense_stage(B, A, p.wd4, p.bd4, 128, 64,  true);
  dense_stage(A, B, p.wd5, p.bd5, 64,  16,  true);
  dense_stage(B, A, p.wd6, p.bd6, 16,  3,   false);
  if (threadIdx.x == 0) {
    float z0 = A[0], z1 = A[1], z2 = A[2];
    float m  = fmaxf(fmaxf(z0, z1), z2);
    float e0 = expf(z0 - m), e1 = expf(z1 - m), e2 = expf(z2 - m);
    float s  = e0 + e1 + e2;
    p.out[b * 3 + 0] = e0 / s;
    p.out[b * 3 + 1] = e1 / s;
    p.out[b * 3 + 2] = e2 / s;
  }
}

// ============================================================================
//                    FALLBACK KERNEL  (R8 champion, verbatim)
// ============================================================================
template<int NBLK>
__device__ void control_role(unsigned* U, int first, int lidx) {
  const int w = threadIdx.x >> 6, lane = threadIdx.x & 63;
  int cand = 1;
  while (cand <= TSTEPS) {
    unsigned v0 = (lane < NBLK)      ? u_load(&U[4 * (first + lane) + w])      : 0xFFFFFFFFu;
    unsigned v1 = (lane + 64 < NBLK) ? u_load(&U[4 * (first + lane + 64) + w]) : 0xFFFFFFFFu;
    unsigned v = v0 < v1 ? v0 : v1;
    if (__all((int)(v >= (unsigned)cand))) {
      if (lane < 16) u_store(&U[1024 + lane * 64 + lidx * 4 + w], (unsigned)cand);
      ++cand;
    }
  }
}

#define FETCH(PP, CC) do { \
  _Pragma("unroll") \
  for (int ii_ = 0; ii_ < C; ++ii_) { \
    const int ks_ = (CC) * C + ii_; \
    if (ks_ < KS) { \
      const int k_ = ks_ * 32 + kg; \
      _Pragma("unroll") \
      for (int m_ = 0; m_ < 2; ++m_) { \
        const int bmv_ = m_ ? bm1 : bm0; \
        uint4 v_ = make_uint4(0u, 0u, 0u, 0u); \
        if constexpr (SEQM) { \
          if (k_ < DIN)        v_ = *(const uint4*)(inP + (size_t)bmv_ * DIN + k_); \
          else if (k_ < KREAL) v_ = *(const uint4*)(inH + (size_t)bmv_ * H + (k_ - DIN)); \
        } else { \
          if (k_ < DIN) { \
            const f16* p_ = inP + (size_t)bmv_ * DIN + k_; \
            if constexpr (SEQIN) { \
              ((uint64_t*)&v_)[0] = *(const uint64_t*)p_; \
              ((uint64_t*)&v_)[1] = *(const uint64_t*)(p_ + 4); \
            } else { \
              ((uint64_t*)&v_)[0] = c_load8(p_); \
              ((uint64_t*)&v_)[1] = c_load8(p_ + 4); \
            } \
          } else if (k_ < KREAL) { \
            const f16* p_ = inH + (size_t)bmv_ * H + (k_ - DIN); \
            ((uint64_t*)&v_)[0] = c_load8(p_); \
            ((uint64_t*)&v_)[1] = c_load8(p_ + 4); \
          } \
        } \
        ab[PP][ii_][m_] = v_; \
      } \
    } \
  } \
} while (0)

#define COMPUTE(PP, CC) do { \
  _Pragma("unroll") \
  for (int ii_ = 0; ii_ < C; ++ii_) { \
    const int ks_ = (CC) * C + ii_; \
    if (ks_ < KS) { \
      const int kb_ = ks_ * 32; \
      h8v bf_[NTI]; \
      _Pragma("unroll") \
      for (int nt_ = 0; nt_ < NTI; ++nt_) \
        bf_[nt_] = *(const h8v*)(wlds + (size_t)(nt_ * 16 + l15) * WROW + kb_ + kg); \
      _Pragma("unroll") \
      for (int m_ = 0; m_ < 2; ++m_) { \
        union { uint4 u; h8v v; } af_; \
        af_.u = ab[PP][ii_][m_]; \
        _Pragma("unroll") \
        for (int nt_ = 0; nt_ < NTI; ++nt_) \
          acc[m_][nt_] = __builtin_amdgcn_mfma_f32_16x16x32_f16(af_.v, bf_[nt_], acc[m_][nt_], 0, 0, 0); \
      } \
    } \
  } \
} while (0)

#define WAITOWN do { \
  bool c_ = (lane != 0) || (rcO >= t); \
  while (!__all((int)c_)) { \
    if (!c_) { rcO = (int)u_load(&relp[LIDX * 4 + w]); c_ = (rcO >= t); } \
  } \
} while (0)

template<int DIN, int H, int NJ, int LIDX, bool SEQIN, int RING>
__device__ void lstm_role(int blk, int bid, const f16* lo_base, f16* ownH,
                          const f16* pack, const float* __restrict__ gbias,
                          const f16* zreg, char* smem, unsigned* U) {
  constexpr bool SEQM = (RING == TSTEPS);
  constexpr int KREAL = DIN + H;
  constexpr int KS    = (KREAL + 31) / 32;
  constexpr int KPAD  = KS * 32;
  constexpr int NGC   = 4 * NJ;
  constexpr int NTI   = NGC / 16;
  constexpr int WROW  = KPAD + 8;
  constexpr int ZROW  = 132;
  constexpr int C     = 6;
  constexpr int NC    = (KS + C - 1) / C;
  constexpr int KSX   = DIN / 32;
  constexpr int CH    = KSX / C;
  static_assert(NC <= 6, "NC");
  static_assert(CH <= NC - 1, "CH");

  const int tid  = threadIdx.x;
  const int w    = tid >> 6, lane = tid & 63;
  const int l15  = lane & 15;
  const int kg   = (lane >> 4) * 8;
  const int bm0  = w * 32 + l15;
  const int bm1  = bm0 + 16;

  f16*   wlds = (f16*)smem;
  float* z    = (float*)(smem + (size_t)NGC * WROW * 2);

  {
    const f16* src = pack + (size_t)blk * NGC * KPAD;
    constexpr int RU = KPAD / 8;
    for (int u = tid; u < NGC * RU; u += NT) {
      const int n = u / RU, k8 = u % RU;
      *(uint4*)(wlds + (size_t)n * WROW + k8 * 8) =
          *(const uint4*)(src + (size_t)n * KPAD + k8 * 8);
    }
  }
  __syncthreads();

  constexpr int JW = NJ / 4;
  const int be  = 32 * w + lane / JW;
  const int jg  = lane % JW;
  const bool epi = (lane < 32 * JW);
  const int j0  = blk * NJ + jg * 4;
  f32x4 bias4[4] = {};
  if (epi) {
    #pragma unroll
    for (int g = 0; g < 4; ++g) bias4[g] = *(const f32x4*)(gbias + (size_t)g * H + j0);
  }
  float cst[4] = {0.f, 0.f, 0.f, 0.f};

  const unsigned* relp = &U[1024 + (bid & 15) * 64];
  int rcI = 0, rcO = 0, rcD = 0;
  (void)rcI; (void)rcD;

  for (int t = 0; t < TSTEPS; ++t) {
    {
      bool c = true;
      if constexpr (LIDX > 0) { if (lane == 0) c = (rcI >= t + 1); }
      if constexpr (CH == 0)  { if (lane == 1) c = (rcO >= t); }
      if constexpr (!SEQM && LIDX < 3) { if (lane == 2) c = (rcD >= t - (RING - 1)); }
      while (!__all((int)c)) {
        if (!c) {
          if constexpr (LIDX > 0) {
            if (lane == 0) { rcI = (int)u_load(&relp[(LIDX - 1) * 4 + w]); c = (rcI >= t + 1); }
          }
          if constexpr (CH == 0) {
            if (lane == 1) { rcO = (int)u_load(&relp[LIDX * 4 + w]); c = (rcO >= t); }
          }
          if constexpr (!SEQM && LIDX < 3) {
            if (lane == 2) { rcD = (int)u_load(&relp[(LIDX + 1) * 4 + w]); c = (rcD >= t - (RING - 1)); }
          }
        }
      }
    }

    const f16* inP = SEQIN ? lo_base + (size_t)t * DIN * BATCH
                           : lo_base + (size_t)(t & (RING - 1)) * DIN * BATCH;
    const f16* inH = (t == 0) ? zreg
                              : ownH + (size_t)((t - 1) & (RING - 1)) * H * BATCH;

    f32x4 acc[2][NTI];
    {
      const f32x4 zz = {0.f, 0.f, 0.f, 0.f};
      #pragma unroll
      for (int m_ = 0; m_ < 2; ++m_)
        #pragma unroll
        for (int nt_ = 0; nt_ < NTI; ++nt_) acc[m_][nt_] = zz;
    }

    uint4 ab[3][C][2];

    FETCH(0, 0);
    if constexpr (NC > 1) { if constexpr (CH == 1) WAITOWN; FETCH(1, 1); }
    if constexpr (NC > 2) { if constexpr (CH == 2) WAITOWN; FETCH(2, 2); }
    COMPUTE(0, 0);
    if constexpr (NC > 1) { if constexpr (NC > 3) { if constexpr (CH == 3) WAITOWN; FETCH(0, 3); } COMPUTE(1, 1); }
    if constexpr (NC > 2) { if constexpr (NC > 4) { if constexpr (CH == 4) WAITOWN; FETCH(1, 4); } COMPUTE(2, 2); }
    if constexpr (NC > 3) { if constexpr (NC > 5) { if constexpr (CH == 5) WAITOWN; FETCH(2, 5); } COMPUTE(0, 3); }
    if constexpr (NC > 4) COMPUTE(1, 4);
    if constexpr (NC > 5) COMPUTE(2, 5);

    #pragma unroll
    for (int m_ = 0; m_ < 2; ++m_)
      #pragma unroll
      for (int nt_ = 0; nt_ < NTI; ++nt_)
        *(f32x4*)(z + (size_t)(nt_ * 16 + l15) * ZROW + w * 32 + m_ * 16 + (lane >> 4) * 4) =
            acc[m_][nt_];

    if (epi) {
      float vi[4], vf[4], vg[4], vo[4];
      #pragma unroll
      for (int q = 0; q < 4; ++q) {
        const int nn = jg * 4 + q;
        vi[q] = z[(size_t)(0 * NJ + nn) * ZROW + be];
        vf[q] = z[(size_t)(1 * NJ + nn) * ZROW + be];
        vg[q] = z[(size_t)(2 * NJ + nn) * ZROW + be];
        vo[q] = z[(size_t)(3 * NJ + nn) * ZROW + be];
      }
      union { f16 h[4]; uint64_t u; } o;
      #pragma unroll
      for (int q = 0; q < 4; ++q) {
        const float ig = sigm(vi[q] + bias4[0][q]);
        const float fg = sigm(vf[q] + bias4[1][q]);
        const float gg = tanhf(vg[q] + bias4[2][q]);
        const float og = sigm(vo[q] + bias4[3][q]);
        cst[q] = fg * cst[q] + ig * gg;
        o.h[q] = (f16)(og * tanhf(cst[q]));
      }
      c_store8(ownH + (size_t)(t & (RING - 1)) * H * BATCH + (size_t)be * H + j0, o.u);
    }
    asm volatile("s_waitcnt vmcnt(0)" ::: "memory");
    if (lane == 0) u_store(&U[4 * bid + w], (unsigned)(t + 1));
  }
}
#undef FETCH
#undef COMPUTE
#undef WAITOWN

constexpr size_t cmax(size_t a, size_t b) { return a > b ? a : b; }
constexpr size_t wlz(int NGC, int KPAD) {
  return (size_t)NGC * (KPAD + 8) * 2 + (size_t)NGC * 132 * 4;
}
static constexpr size_t SMEM_FB =
    cmax(cmax(wlz(32, 704), wlz(16, 1056)),
         cmax(cmax(wlz(32, 672), wlz(32, 512)), (size_t)4096));
static_assert(SMEM_FB <= 65536, "LDS fb");

template<int RING>
__global__ __launch_bounds__(NT, 1) void fused_fb(KParams p) {
  using L = WS<RING>;
  cg::grid_group grid = cg::this_grid();
  __shared__ __attribute__((aligned(16))) char smem[SMEM_FB];

  char* ws = p.ws;
  unsigned* U = (unsigned*)(ws + L::BAR);
  const f16* zreg = (const f16*)(ws + L::ZERO);
  const int tid  = threadIdx.x;
  const int bid  = blockIdx.x;
  const int gtid = bid * NT + tid;
  const int gstr = NGRID * NT;

  prepack_layer(p.k1, p.r1, (f16*)(ws + L::PK1), 64,  640, 8, 704,  TB1, gtid, gstr);
  prepack_layer(p.k2, p.r2, (f16*)(ws + L::PK2), 640, 400, 4, 1056, TB2, gtid, gstr);
  prepack_layer(p.k3, p.r3, (f16*)(ws + L::PK3), 400, 256, 8, 672,  TB3, gtid, gstr);
  prepack_layer(p.k4, p.r4, (f16*)(ws + L::PK4), 256, 256, 8, 512,  TB4, gtid, gstr);
  {
    f16* xT = (f16*)(ws + L::XT);
    const long total = (long)TSTEPS * BATCH * 8;
    for (long u = gtid; u < total; u += gstr) {
      const int  d8 = (int)(u & 7);
      const long r  = u >> 3;
      const int  b  = (int)(r & (BATCH - 1));
      const int  t  = (int)(r >> 7);
      const float* src = p.x + ((size_t)b * TSTEPS + t) * 64 + d8 * 8;
      const float4 v0 = *(const float4*)src;
      const float4 v1 = *(const float4*)(src + 4);
      h8v o;
      o[0] = (f16)v0.x; o[1] = (f16)v0.y; o[2] = (f16)v0.z; o[3] = (f16)v0.w;
      o[4] = (f16)v1.x; o[5] = (f16)v1.y; o[6] = (f16)v1.z; o[7] = (f16)v1.w;
      *(h8v*)(xT + ((size_t)t * BATCH + b) * 64 + d8 * 8) = o;
    }
  }

  grid.sync();
  acq_fence();

  constexpr int TRB2 = TB1, TRB3 = TB1 + TB2, TRB4 = TB1 + TB2 + TB3;
  if (bid >= TNB) {
    const int l = bid - TNB;
    if (l == 0)      control_role<TB1>(U, 0,    0);
    else if (l == 1) control_role<TB2>(U, TRB2, 1);
    else if (l == 2) control_role<TB3>(U, TRB3, 2);
    else             control_role<TB4>(U, TRB4, 3);
  } else if (bid < TRB2) {
    lstm_role< 64, 640, 8, 0, true , RING>(bid, bid, (const f16*)(ws + L::XT),
        (f16*)(ws + L::H1), (const f16*)(ws + L::PK1), p.b1, zreg, smem, U);
  } else if (bid < TRB3) {
    lstm_role<640, 400, 4, 1, false, RING>(bid - TRB2, bid, (const f16*)(ws + L::H1),
        (f16*)(ws + L::H2), (const f16*)(ws + L::PK2), p.b2, zreg, smem, U);
  } else if (bid < TRB4) {
    lstm_role<400, 256, 8, 2, false, RING>(bid - TRB3, bid, (const f16*)(ws + L::H2),
        (f16*)(ws + L::H3), (const f16*)(ws + L::PK3), p.b3, zreg, smem, U);
  } else {
    lstm_role<256, 256, 8, 3, false, RING>(bid - TRB4, bid, (const f16*)(ws + L::H3),
        (f16*)(ws + L::H4), (const f16*)(ws + L::PK4), p.b4, zreg, smem, U);
  }

  if (bid < BATCH) {
    {
      int cond = 1;
      if (tid < 4 * TB4) cond = ((int)u_load(&U[4 * (TRB4 + (tid >> 2)) + (tid & 3)]) >= TSTEPS);
      while (!__syncthreads_and(cond)) {
        if (!cond) cond = ((int)u_load(&U[4 * (TRB4 + (tid >> 2)) + (tid & 3)]) >= TSTEPS);
      }
    }
    const f16* h4 = (const f16*)(ws + L::H4)
                  + (size_t)((TSTEPS - 1) & (RING - 1)) * 256 * BATCH + (size_t)bid * 256;
    dense_head(p, h4, (float*)smem, (float*)smem + 512, bid);
  }
}

// ============================================================================
//          XCD-TEAM KERNEL  (intra-L2 recurrence sync, repaired flags)
// ============================================================================
// teams: xcd -> layer = xcd>>1, half = xcd&1; 1 block/CU forced by 125 KB LDS.
static constexpr size_t SMEM_X = 125440;   // L1 team: 80*648*2 + 80*68*4

#define TFETCH(PP, CC) do { \
  _Pragma("unroll") \
  for (int ii_ = 0; ii_ < C; ++ii_) { \
    const int ks_ = (CC) * C + ii_; \
    if (ks_ < KS) { \
      const int k_ = ks_ * 32 + kg; \
      uint4 v_ = make_uint4(0u, 0u, 0u, 0u); \
      if (k_ < DIN)        v_ = *(const uint4*)(inP + (size_t)bm * DIN + k_); \
      else if (k_ < KREAL) v_ = *(const uint4*)(inH + (size_t)bm * H + (k_ - DIN)); \
      ab[PP][ii_] = v_; \
    } \
  } \
} while (0)

#define TCOMPUTE(PP, CC) do { \
  _Pragma("unroll") \
  for (int ii_ = 0; ii_ < C; ++ii_) { \
    const int ks_ = (CC) * C + ii_; \
    if (ks_ < KS) { \
      const int kb_ = ks_ * 32; \
      h8v bf_[NTI]; \
      _Pragma("unroll") \
      for (int nt_ = 0; nt_ < NTI; ++nt_) { \
        const int n_ = nt_ * 16 + l15; \
        if (kb_ >= LDSK0 && kb_ < LDSK1) \
          bf_[nt_] = *(const h8v*)(wlds + (size_t)n_ * WROW + (kb_ - LDSK0) + kg); \
        else \
          bf_[nt_] = *(const h8v*)(gpk + (size_t)n_ * KPAD + kb_ + kg); \
      } \
      union { uint4 u; h8v v; } af_; af_.u = ab[PP][ii_]; \
      _Pragma("unroll") \
      for (int nt_ = 0; nt_ < NTI; ++nt_) \
        acc[nt_] = __builtin_amdgcn_mfma_f32_16x16x32_f16(af_.v, bf_[nt_], acc[nt_], 0, 0, 0); \
    } \
  } \
} while (0)

// own-peer wait (L2-atomic poll), timeout-guarded; slot0 watermark publish (sc1)
#define TWAITOWN do { \
  if (!dead) { \
    int grd_ = 0; \
    bool c_ = (lane >= TS) || (rcO >= t); \
    while (!__all((int)c_)) { \
      if (++grd_ > SPINMAX) { dead = 1; break; } \
      if (!c_) { \
        rcO = (int)f_load(Fo + lane * 4 + w); c_ = (rcO >= t); \
        if (!c_) __builtin_amdgcn_s_sleep(1); \
      } \
    } \
  } \
  if (slot == 0 && lane == 0) { \
    _Pragma("unroll") \
    for (int rp_ = 0; rp_ < 4; ++rp_) u_store(WMo + rp_ * 4 + w, (unsigned)t); \
  } \
} while (0)

template<int DIN, int H, int NJL, int TS, int LIDX, int LDSK0, int LDSK1>
__device__ void team_role(int slot, int xcd, int half,
                          const f16* lo_base, f16* ownH, const f16* pack,
                          const float* __restrict__ gbias, const f16* zreg,
                          char* smem, unsigned* Bu) {
  constexpr int KREAL = DIN + H;
  constexpr int KPAD  = ((KREAL + 31) / 32) * 32;
  constexpr int KS    = KPAD / 32;
  constexpr int NGC   = 4 * NJL;
  constexpr int NTI   = NGC / 16;
  constexpr int LKW   = LDSK1 - LDSK0;
  constexpr int WROW  = LKW + 8;
  constexpr int ZROW  = 68;
  constexpr int C     = 6;
  constexpr int NC    = (KS + C - 1) / C;
  constexpr int CH    = (DIN / 32) / C;
  static_assert(NC <= 6 && CH <= NC - 1, "geom");
  static_assert((size_t)NGC * WROW * 2 + (size_t)NGC * ZROW * 4 <= SMEM_X, "lds");

  const int tid = threadIdx.x, w = tid >> 6, lane = tid & 63;
  const int l15 = lane & 15, kg = (lane >> 4) * 8;
  const int bm  = half * 64 + 16 * w + l15;     // global batch row (A operand)

  f16*   wlds = (f16*)smem;
  float* z    = (float*)(smem + (size_t)NGC * WROW * 2);
  const f16* gpk = pack + (size_t)slot * NGC * KPAD;

  // LDS-resident weight stripe (k in [LDSK0, LDSK1))
  {
    constexpr int RU = LKW / 8;
    for (int u = tid; u < NGC * RU; u += NT) {
      const int n = u / RU, k8 = u % RU;
      *(uint4*)(wlds + (size_t)n * WROW + k8 * 8) =
          *(const uint4*)(gpk + (size_t)n * KPAD + LDSK0 + k8 * 8);
    }
  }
  __syncthreads();

  // epilogue items: per wave 16 batches x JW j-groups
  constexpr int JW    = NJL / 4;
  constexpr int NITEM = 16 * JW;
  constexpr int NIT   = (NITEM + 63) / 64;
  float cst[NIT][4] = {};
  f32x4 bias4[NIT][4];
  #pragma unroll
  for (int ii = 0; ii < NIT; ++ii) {
    const int it = ii * 64 + lane;
    if (it < NITEM) {
      const int g4 = it % JW;
      const int j0 = slot * NJL + g4 * 4;
      #pragma unroll
      for (int g = 0; g < 4; ++g) bias4[ii][g] = *(const f32x4*)(gbias + (size_t)g * H + j0);
    }
  }

  unsigned* Fo  = Bu + 16 + xcd * 128;              // + slot*4 + w
  unsigned* WMo = Bu + 1040 + xcd * 16;             // + rep*4 + w
  const unsigned* WMp = Bu + 1040 + (xcd - 2) * 16; // prev layer, same half
  const int rep = slot & 3;
  int rcP = 0, rcO = 0;
  int dead = 0;

  for (int t = 0; t < TSTEPS; ++t) {
    // ---- top wait: prev-layer watermark (sc1); own peers if CH==0; guarded ----
    if (!dead) {
      int grd = 0;
      bool c = true;
      if constexpr (LIDX > 0) { if (lane == 0) c = (rcP >= t + 1); }
      if constexpr (CH == 0)  { if (lane < TS) c = c && (rcO >= t); }
      while (!__all((int)c)) {
        if (++grd > SPINMAX) { dead = 1; break; }
        if (!c) {
          if constexpr (LIDX > 0)
            if (lane == 0 && rcP < t + 1) rcP = (int)u_load(WMp + rep * 4 + w);
          if constexpr (CH == 0)
            if (lane < TS && rcO < t) rcO = (int)f_load(Fo + lane * 4 + w);
          c = true;
          if constexpr (LIDX > 0) { if (lane == 0) c = (rcP >= t + 1); }
          if constexpr (CH == 0)  { if (lane < TS) c = c && (rcO >= t); }
          if (!c) __builtin_amdgcn_s_sleep(1);
        }
      }
    }
    if constexpr (CH == 0) {
      if (slot == 0 && lane == 0) {
        #pragma unroll
        for (int rp = 0; rp < 4; ++rp) u_store(WMo + rp * 4 + w, (unsigned)t);
      }
    }

    const f16* inP = lo_base + (size_t)t * DIN * BATCH;
    const f16* inH = (t == 0) ? zreg : ownH + (size_t)(t - 1) * H * BATCH;

    f32x4 acc[NTI];
    {
      const f32x4 zz = {0.f, 0.f, 0.f, 0.f};
      #pragma unroll
      for (int nt_ = 0; nt_ < NTI; ++nt_) acc[nt_] = zz;
    }
    uint4 ab[3][C];

    TFETCH(0, 0);
    if constexpr (NC > 1) { if constexpr (CH == 1) TWAITOWN; TFETCH(1, 1); }
    if constexpr (NC > 2) { if constexpr (CH == 2) TWAITOWN; TFETCH(2, 2); }
    TCOMPUTE(0, 0);
    if constexpr (NC > 1) { if constexpr (NC > 3) { if constexpr (CH == 3) TWAITOWN; TFETCH(0, 3); } TCOMPUTE(1, 1); }
    if constexpr (NC > 2) { if constexpr (NC > 4) { if constexpr (CH == 4) TWAITOWN; TFETCH(1, 4); } TCOMPUTE(2, 2); }
    if constexpr (NC > 3) { if constexpr (NC > 5) { if constexpr (CH == 5) TWAITOWN; TFETCH(2, 5); } TCOMPUTE(0, 3); }
    if constexpr (NC > 4) TCOMPUTE(1, 4);
    if constexpr (NC > 5) TCOMPUTE(2, 5);

    // ---- D -> z[gatecol][teambatch] (wave-local columns, no barrier) ----
    #pragma unroll
    for (int nt_ = 0; nt_ < NTI; ++nt_)
      *(f32x4*)(z + (size_t)(nt_ * 16 + l15) * ZROW + 16 * w + (lane >> 4) * 4) = acc[nt_];

    // ---- epilogue: gates, state, coalesced 8B sc1 h store ----
    #pragma unroll
    for (int ii = 0; ii < NIT; ++ii) {
      const int it = ii * 64 + lane;
      if (it < NITEM) {
        const int bb = it / JW, g4 = it % JW;
        const int beL = 16 * w + bb;
        const int j0  = slot * NJL + g4 * 4;
        union { f16 h[4]; uint64_t u; } o;
        #pragma unroll
        for (int q = 0; q < 4; ++q) {
          const int nn = g4 * 4 + q;
          const float vi = z[(size_t)(0 * NJL + nn) * ZROW + beL];
          const float vf = z[(size_t)(1 * NJL + nn) * ZROW + beL];
          const float vg = z[(size_t)(2 * NJL + nn) * ZROW + beL];
          const float vo = z[(size_t)(3 * NJL + nn) * ZROW + beL];
          const float ig = sigm(vi + bias4[ii][0][q]);
          const float fg = sigm(vf + bias4[ii][1][q]);
          const float gg = tanhf(vg + bias4[ii][2][q]);
          const float og = sigm(vo + bias4[ii][3][q]);
          cst[ii][q] = fg * cst[ii][q] + ig * gg;
          o.h[q] = (f16)(og * tanhf(cst[ii][q]));
        }
        c_store8(ownH + (size_t)t * H * BATCH + (size_t)(half * 64 + beL) * H + j0, o.u);
      }
    }
    asm volatile("s_waitcnt vmcnt(0)" ::: "memory");   // drain sc1 h-stores
    if (lane == 0) f_store(Fo + slot * 4 + w, (unsigned)(t + 1));  // L2 flag publish
  }

  // ---- final watermark: all peers done 512 -> WM = TSTEPS (guarded) ----
  if (slot == 0) {
    int grd = 0;
    bool c = (lane >= TS);
    int rcF = 0;
    while (!__all((int)c)) {
      if (++grd > SPINMAX) break;
      if (!c) {
        rcF = (int)f_load(Fo + lane * 4 + w);
        c = (rcF >= TSTEPS);
        if (!c) __builtin_amdgcn_s_sleep(1);
      }
    }
    if (lane == 0) {
      #pragma unroll
      for (int rp = 0; rp < 4; ++rp) u_store(WMo + rp * 4 + w, (unsigned)TSTEPS);
    }
  }
}
#undef TFETCH
#undef TCOMPUTE
#undef TWAITOWN

__global__ __launch_bounds__(NT, 1) void fused_xcd(KParams p) {
  using L = WS<TSTEPS>;
  cg::grid_group grid = cg::this_grid();
  __shared__ __attribute__((aligned(16))) char smem[SMEM_X];
  __shared__ int sxcd, sslot;

  char* ws = p.ws;
  unsigned* Bu = (unsigned*)(ws + L::BAR);
  const f16* zreg = (const f16*)(ws + L::ZERO);
  const int tid = threadIdx.x;
  const int bid = blockIdx.x;
  const int gtid = bid * NT + tid;
  const int gstr = NGX * NT;

  // ---- role probe: actual XCD + team slot (placement-agnostic correctness) ----
  if (tid == 0) {
    const int x = xcc_id();
    sxcd = x;
    sslot = (int)__hip_atomic_fetch_add(&Bu[x], 1u, __ATOMIC_RELAXED, __HIP_MEMORY_SCOPE_AGENT);
  }

  // ---- phase 0: prepack (team geometry) + x transpose ----
  prepack_layer(p.k1, p.r1, (f16*)(ws + L::PK1), 64,  640, 20, 704,  32, gtid, gstr);
  prepack_layer(p.k2, p.r2, (f16*)(ws + L::PK2), 640, 400, 16, 1056, 25, gtid, gstr);
  prepack_layer(p.k3, p.r3, (f16*)(ws + L::PK3), 400, 256, 8,  672,  32, gtid, gstr);
  prepack_layer(p.k4, p.r4, (f16*)(ws + L::PK4), 256, 256, 8,  512,  32, gtid, gstr);
  {
    f16* xT = (f16*)(ws + L::XT);
    const long total = (long)TSTEPS * BATCH * 8;
    for (long u = gtid; u < total; u += gstr) {
      const int  d8 = (int)(u & 7);
      const long r  = u >> 3;
      const int  b  = (int)(r & (BATCH - 1));
      const int  t  = (int)(r >> 7);
      const float* src = p.x + ((size_t)b * TSTEPS + t) * 64 + d8 * 8;
      const float4 v0 = *(const float4*)src;
      const float4 v1 = *(const float4*)(src + 4);
      h8v o;
      o[0] = (f16)v0.x; o[1] = (f16)v0.y; o[2] = (f16)v0.z; o[3] = (f16)v0.w;
      o[4] = (f16)v1.x; o[5] = (f16)v1.y; o[6] = (f16)v1.z; o[7] = (f16)v1.w;
      *(h8v*)(xT + ((size_t)t * BATCH + b) * 64 + d8 * 8) = o;
    }
  }

  grid.sync();
  acq_fence();
  __syncthreads();

  const int xcd = sxcd, slot = sslot;
  const int layer = xcd >> 1, half = xcd & 1;

  // ---- phase 1: XCD-team LSTM scan ----
  if (layer == 0) {
    if (slot < 32) team_role< 64, 640, 20, 32, 0,  64,  704>(slot, xcd, half,
        (const f16*)(ws + L::XT), (f16*)(ws + L::H1), (const f16*)(ws + L::PK1),
        p.b1, zreg, smem, Bu);
  } else if (layer == 1) {
    if (slot < 25) team_role<640, 400, 16, 25, 1,   0,  640>(slot, xcd, half,
        (const f16*)(ws + L::H1), (f16*)(ws + L::H2), (const f16*)(ws + L::PK2),
        p.b2, zreg, smem, Bu);
  } else if (layer == 2) {
    if (slot < 32) team_role<400, 256,  8, 32, 2,   0,  672>(slot, xcd, half,
        (const f16*)(ws + L::H2), (f16*)(ws + L::H3), (const f16*)(ws + L::PK3),
        p.b3, zreg, smem, Bu);
  } else {
    if (slot < 32) team_role<256, 256,  8, 32, 3,   0,  512>(slot, xcd, half,
        (const f16*)(ws + L::H3), (f16*)(ws + L::H4), (const f16*)(ws + L::PK4),
        p.b4, zreg, smem, Bu);
  }

  // ---- phase 2: dense head (guarded wait) ----
  if (bid < BATCH) {
    const int hb = (bid >= 64) ? 1 : 0;
    {
      int grd = 0;
      int cond = 1;
      if (tid < 4)
        cond = ((int)u_load(Bu + 1040 + (6 + hb) * 16 + (bid & 3) * 4 + tid) >= TSTEPS);
      while (!__syncthreads_and(cond)) {
        if (++grd > SPINMAX) break;
        if (!cond) {
          cond = ((int)u_load(Bu + 1040 + (6 + hb) * 16 + (bid & 3) * 4 + tid) >= TSTEPS);
          if (!cond) __builtin_amdgcn_s_sleep(1);
        }
      }
    }
    const f16* h4 = (const f16*)(ws + L::H4)
                  + (size_t)(TSTEPS - 1) * 256 * BATCH + (size_t)bid * 256;
    dense_head(p, h4, (float*)smem, (float*)smem + 512, bid);
  }
}

// ---------------- launch ----------------
extern "C" void kernel_launch(void* const* d_in, const int* in_sizes, int n_in,
                              void* d_out, int out_size, void* d_ws, size_t ws_size,
                              hipStream_t stream) {
  (void)in_sizes; (void)n_in; (void)out_size;
  KParams prm;
  prm.x  = (const float*)d_in[0];
  prm.k1 = (const float*)d_in[1];  prm.r1 = (const float*)d_in[2];  prm.b1 = (const float*)d_in[3];
  prm.k2 = (const float*)d_in[4];  prm.r2 = (const float*)d_in[5];  prm.b2 = (const float*)d_in[6];
  prm.k3 = (const float*)d_in[7];  prm.r3 = (const float*)d_in[8];  prm.b3 = (const float*)d_in[9];
  prm.k4 = (const float*)d_in[10]; prm.r4 = (const float*)d_in[11]; prm.b4 = (const float*)d_in[12];
  prm.wd1 = (const float*)d_in[13]; prm.bd1 = (const float*)d_in[14];
  prm.wd2 = (const float*)d_in[15]; prm.bd2 = (const float*)d_in[16];
  prm.wd3 = (const float*)d_in[17]; prm.bd3 = (const float*)d_in[18];
  prm.wd4 = (const float*)d_in[19]; prm.bd4 = (const float*)d_in[20];
  prm.wd5 = (const float*)d_in[21]; prm.bd5 = (const float*)d_in[22];
  prm.wd6 = (const float*)d_in[23]; prm.bd6 = (const float*)d_in[24];
  prm.out = (float*)d_out;
  prm.ws  = (char*)d_ws;

  const bool big = ws_size >= WS<TSTEPS>::END;
  const size_t bar_off = big ? WS<TSTEPS>::BAR : WS<4>::BAR;
  hipMemsetAsync((char*)d_ws + bar_off, 0, 8192 + 163840, stream);

  void* args[] = { &prm };
  if (big) {
    // XCD-team kernel needs 1 block/CU (forced by 125 KB LDS) and 256 co-resident blocks
    int maxb = 0;
    hipOccupancyMaxActiveBlocksPerMultiprocessor(&maxb, (const void*)fused_xcd, NT, 0);
    hipError_t e = hipErrorUnknown;
    if (maxb >= 1) {
      e = hipLaunchCooperativeKernel((void*)fused_xcd, dim3(NGX), dim3(NT), args, 0, stream);
    }
    if (e != hipSuccess) {
      hipLaunchCooperativeKernel((void*)fused_fb<TSTEPS>, dim3(NGRID), dim3(NT), args, 0, stream);
    }
  } else {
    hipLaunchCooperativeKernel((void*)fused_fb<4>, dim3(NGRID), dim3(NT), args, 0, stream);
  }
}

// Round 13
// 4836.802 us; speedup vs baseline: 360.9542x; 113.9415x over previous
//
#include <hip/hip_runtime.h>
#include <hip/hip_cooperative_groups.h>
#include <cstdint>
#include <cstddef>

namespace cg = cooperative_groups;

typedef _Float16 f16;
typedef _Float16 h8v  __attribute__((ext_vector_type(8)));
typedef float    f32x4 __attribute__((ext_vector_type(4)));

static constexpr int BATCH  = 128;
static constexpr int TSTEPS = 512;
static constexpr int NT     = 256;

// worker blocks per layer (NJ = hidden units per block: 8,4,8,8)
static constexpr int TB1 = 80, TB2 = 100, TB3 = 32, TB4 = 32;
static constexpr int TNB   = TB1 + TB2 + TB3 + TB4;   // 244
static constexpr int NGRID = TNB + 4;                 // + 4 control blocks

// ---------------- workspace layout (byte offsets) ----------------
// all h tensors batch-major: [slot][b][j]  (f16)
template<int RING> struct WS {
  static constexpr size_t XT  = 0;                                   // f16 [512][128][64]
  static constexpr size_t H1  = XT + 512ull * 128 * 64 * 2;          // f16 [RING][128][640]
  static constexpr size_t H2  = H1 + (size_t)RING * 128 * 640 * 2 + 64;
  static constexpr size_t H3  = H2 + (size_t)RING * 128 * 400 * 2 + 64;
  static constexpr size_t H4  = H3 + (size_t)RING * 128 * 256 * 2 + 64;
  static constexpr size_t PK1 = H4 + (size_t)RING * 128 * 256 * 2 + 64; // f16 [TB][4NJ][KPAD]
  static constexpr size_t PK2 = PK1 + (size_t)TB1 * 32 * 704  * 2;
  static constexpr size_t PK3 = PK2 + (size_t)TB2 * 16 * 1056 * 2;
  static constexpr size_t PK4 = PK3 + (size_t)TB3 * 32 * 672  * 2;
  static constexpr size_t BAR = PK4 + (size_t)TB4 * 32 * 512  * 2;   // 8 KB sync area
  static constexpr size_t ZERO= BAR + 8192;                          // zeroed h[-1] region
  static constexpr size_t END = ZERO + 163840;                       // 128*640+slack f16
};
// U[4*bid + w] (0..975): per-WAVE step flags
// U[1024 + rep*64 + lidx*4 + w]: per-(layer,wave) watermark replicas, rep 0..15

struct KParams {
  const float *x;
  const float *k1, *r1, *b1, *k2, *r2, *b2, *k3, *r3, *b3, *k4, *r4, *b4;
  const float *wd1, *bd1, *wd2, *bd2, *wd3, *bd3, *wd4, *bd4, *wd5, *bd5, *wd6, *bd6;
  float *out;
  char *ws;
};

__device__ __forceinline__ float sigm(float v) { return 1.f / (1.f + expf(-v)); }

// ---- agent-scope (cross-XCD coherent) primitives: flags + h publish ----
__device__ __forceinline__ uint64_t c_load8(const void* p) {
  return __hip_atomic_load((const uint64_t*)p, __ATOMIC_RELAXED, __HIP_MEMORY_SCOPE_AGENT);
}
__device__ __forceinline__ void c_store8(void* p, uint64_t v) {
  __hip_atomic_store((uint64_t*)p, v, __ATOMIC_RELAXED, __HIP_MEMORY_SCOPE_AGENT);
}
__device__ __forceinline__ unsigned short c_load2(const void* p) {
  return __hip_atomic_load((const unsigned short*)p, __ATOMIC_RELAXED, __HIP_MEMORY_SCOPE_AGENT);
}
__device__ __forceinline__ unsigned u_load(const unsigned* p) {
  return __hip_atomic_load(p, __ATOMIC_RELAXED, __HIP_MEMORY_SCOPE_AGENT);
}
__device__ __forceinline__ void u_store(unsigned* p, unsigned v) {
  __hip_atomic_store(p, v, __ATOMIC_RELAXED, __HIP_MEMORY_SCOPE_AGENT);
}
__device__ __forceinline__ void acq_fence() {
  __builtin_amdgcn_fence(__ATOMIC_ACQUIRE, "agent");
}

// ---------------- per-layer control block: 4 independent wave-engines ----------------
// wave w publishes watermark rel[lidx][w] = min step completed by all layer blocks' wave w
template<int NBLK>
__device__ void control_role(unsigned* U, int first, int lidx) {
  const int w = threadIdx.x >> 6, lane = threadIdx.x & 63;
  int cand = 1;
  while (cand <= TSTEPS) {
    unsigned v0 = (lane < NBLK)      ? u_load(&U[4 * (first + lane) + w])      : 0xFFFFFFFFu;
    unsigned v1 = (lane + 64 < NBLK) ? u_load(&U[4 * (first + lane + 64) + w]) : 0xFFFFFFFFu;
    unsigned v = v0 < v1 ? v0 : v1;
    if (__all((int)(v >= (unsigned)cand))) {
      if (lane < 16) u_store(&U[1024 + lane * 64 + lidx * 4 + w], (unsigned)cand);
      ++cand;
    }
  }
}

// ---------------- weight prepack: pack[blk][n][k], n = gate*NJ + jj, f16, zero-padded K ----------------
__device__ void prepack_layer(const float* __restrict__ gk, const float* __restrict__ gr,
                              f16* __restrict__ pack, int DIN, int H, int NJ, int KPAD,
                              int TB, int gtid, int gstr) {
  const int KREAL = DIN + H;
  const int NGC = 4 * NJ;
  const long total = (long)TB * NGC * KPAD;
  for (long e = gtid; e < total; e += gstr) {
    const int  k   = (int)(e % KPAD);
    const long r   = e / KPAD;
    const int  n   = (int)(r % NGC);
    const int  blk = (int)(r / NGC);
    const int  g   = n / NJ, jj = n % NJ;
    const int  j   = blk * NJ + jj;
    float v = 0.f;
    if (k < DIN)        v = gk[(size_t)k * 4 * H + (size_t)g * H + j];
    else if (k < KREAL) v = gr[(size_t)(k - DIN) * 4 * H + (size_t)g * H + j];
    pack[e] = (f16)v;
  }
}

// ---------------- MFMA LSTM layer role (fully per-wave step loop) ----------------
// FETCH(buf, chunk): A-fragment loads for one chunk of C ksteps.
// Big path (RING==TSTEPS): PLAIN cached uint4 loads — h-ring addresses are
// write-once per run, so cold-miss L2 fills are coherent (validated r3) and
// redundant same-XCD reads become L2 hits. Fallback path: sc1 8B loads.
#define FETCH(PP, CC) do { \
  _Pragma("unroll") \
  for (int ii_ = 0; ii_ < C; ++ii_) { \
    const int ks_ = (CC) * C + ii_; \
    if (ks_ < KS) { \
      const int k_ = ks_ * 32 + kg; \
      _Pragma("unroll") \
      for (int m_ = 0; m_ < 2; ++m_) { \
        const int bmv_ = m_ ? bm1 : bm0; \
        uint4 v_ = make_uint4(0u, 0u, 0u, 0u); \
        if constexpr (SEQM) { \
          if (k_ < DIN)        v_ = *(const uint4*)(inP + (size_t)bmv_ * DIN + k_); \
          else if (k_ < KREAL) v_ = *(const uint4*)(inH + (size_t)bmv_ * H + (k_ - DIN)); \
        } else { \
          if (k_ < DIN) { \
            const f16* p_ = inP + (size_t)bmv_ * DIN + k_; \
            if constexpr (SEQIN) { \
              ((uint64_t*)&v_)[0] = *(const uint64_t*)p_; \
              ((uint64_t*)&v_)[1] = *(const uint64_t*)(p_ + 4); \
            } else { \
              ((uint64_t*)&v_)[0] = c_load8(p_); \
              ((uint64_t*)&v_)[1] = c_load8(p_ + 4); \
            } \
          } else if (k_ < KREAL) { \
            const f16* p_ = inH + (size_t)bmv_ * H + (k_ - DIN); \
            ((uint64_t*)&v_)[0] = c_load8(p_); \
            ((uint64_t*)&v_)[1] = c_load8(p_ + 4); \
          } \
        } \
        ab[PP][ii_][m_] = v_; \
      } \
    } \
  } \
} while (0)

// COMPUTE(buf, chunk): B-fragments from LDS + MFMAs for one chunk
#define COMPUTE(PP, CC) do { \
  _Pragma("unroll") \
  for (int ii_ = 0; ii_ < C; ++ii_) { \
    const int ks_ = (CC) * C + ii_; \
    if (ks_ < KS) { \
      const int kb_ = ks_ * 32; \
      h8v bf_[NTI]; \
      _Pragma("unroll") \
      for (int nt_ = 0; nt_ < NTI; ++nt_) \
        bf_[nt_] = *(const h8v*)(wlds + (size_t)(nt_ * 16 + l15) * WROW + kb_ + kg); \
      _Pragma("unroll") \
      for (int m_ = 0; m_ < 2; ++m_) { \
        union { uint4 u; h8v v; } af_; \
        af_.u = ab[PP][ii_][m_]; \
        _Pragma("unroll") \
        for (int nt_ = 0; nt_ < NTI; ++nt_) \
          acc[m_][nt_] = __builtin_amdgcn_mfma_f32_16x16x32_f16(af_.v, bf_[nt_], acc[m_][nt_], 0, 0, 0); \
      } \
    } \
  } \
} while (0)

// deferred own-peer wait (per-wave): lane 0 polls own-layer wave-w watermark
#define WAITOWN do { \
  bool c_ = (lane != 0) || (rcO >= t); \
  while (!__all((int)c_)) { \
    if (!c_) { rcO = (int)u_load(&relp[LIDX * 4 + w]); c_ = (rcO >= t); } \
  } \
} while (0)

template<int DIN, int H, int NJ, int LIDX, bool SEQIN, int RING>
__device__ void lstm_role(int blk, int bid, const f16* lo_base, f16* ownH,
                          const f16* pack, const float* __restrict__ gbias,
                          const f16* zreg, char* smem, unsigned* U) {
  constexpr bool SEQM = (RING == TSTEPS);
  constexpr int KREAL = DIN + H;
  constexpr int KS    = (KREAL + 31) / 32;
  constexpr int KPAD  = KS * 32;
  constexpr int NGC   = 4 * NJ;
  constexpr int NTI   = NGC / 16;          // N-tiles (1 or 2)
  constexpr int WROW  = KPAD + 8;          // weight LDS row (f16)
  constexpr int ZROW  = 132;               // z LDS row (f32)
  constexpr int C     = 6;                 // ksteps per chunk
  constexpr int NC    = (KS + C - 1) / C;
  constexpr int KSX   = DIN / 32;          // ksteps strictly below this are pure-x
  constexpr int CH    = KSX / C;           // first chunk that may touch own-h
  static_assert(NC <= 6, "NC");
  static_assert(CH <= NC - 1, "CH");
  static_assert(NGC % 16 == 0 && (DIN % 8) == 0 && (KREAL % 8) == 0, "geom");

  const int tid  = threadIdx.x;
  const int w    = tid >> 6, lane = tid & 63;
  const int l15  = lane & 15;
  const int kg   = (lane >> 4) * 8;
  const int bm0  = w * 32 + l15;
  const int bm1  = bm0 + 16;

  f16*   wlds = (f16*)smem;
  float* z    = (float*)(smem + (size_t)NGC * WROW * 2);

  // ---- load this block's weights to LDS once ----
  {
    const f16* src = pack + (size_t)blk * NGC * KPAD;
    constexpr int RU = KPAD / 8;
    for (int u = tid; u < NGC * RU; u += NT) {
      const int n = u / RU, k8 = u % RU;
      *(uint4*)(wlds + (size_t)n * WROW + k8 * 8) =
          *(const uint4*)(src + (size_t)n * KPAD + k8 * 8);
    }
  }
  __syncthreads();   // only barrier: weights visible to all waves

  // ---- per-wave epilogue ownership: lane -> (batch be in wave range, 4 consecutive j) ----
  constexpr int JW = NJ / 4;               // j-groups per batch (2 or 1)
  const int be  = 32 * w + lane / JW;
  const int jg  = lane % JW;
  const bool epi = (lane < 32 * JW);
  const int j0  = blk * NJ + jg * 4;
  f32x4 bias4[4] = {};
  if (epi) {
    #pragma unroll
    for (int g = 0; g < 4; ++g) bias4[g] = *(const f32x4*)(gbias + (size_t)g * H + j0);
  }
  float cst[4] = {0.f, 0.f, 0.f, 0.f};

  const unsigned* relp = &U[1024 + (bid & 15) * 64];
  int rcI = 0, rcO = 0, rcD = 0;
  (void)rcI; (void)rcD;

  for (int t = 0; t < TSTEPS; ++t) {
    // ---- per-wave dataflow wait: parallel lanes, no block barrier ----
    {
      bool c = true;
      if constexpr (LIDX > 0) { if (lane == 0) c = (rcI >= t + 1); }
      if constexpr (CH == 0)  { if (lane == 1) c = (rcO >= t); }
      if constexpr (!SEQM && LIDX < 3) { if (lane == 2) c = (rcD >= t - (RING - 1)); }
      while (!__all((int)c)) {
        if (!c) {
          if constexpr (LIDX > 0) {
            if (lane == 0) { rcI = (int)u_load(&relp[(LIDX - 1) * 4 + w]); c = (rcI >= t + 1); }
          }
          if constexpr (CH == 0) {
            if (lane == 1) { rcO = (int)u_load(&relp[LIDX * 4 + w]); c = (rcO >= t); }
          }
          if constexpr (!SEQM && LIDX < 3) {
            if (lane == 2) { rcD = (int)u_load(&relp[(LIDX + 1) * 4 + w]); c = (rcD >= t - (RING - 1)); }
          }
        }
      }
    }

    const f16* inP = SEQIN ? lo_base + (size_t)t * DIN * BATCH
                           : lo_base + (size_t)(t & (RING - 1)) * DIN * BATCH;
    const f16* inH = (t == 0) ? zreg
                              : ownH + (size_t)((t - 1) & (RING - 1)) * H * BATCH;

    f32x4 acc[2][NTI];
    {
      const f32x4 zz = {0.f, 0.f, 0.f, 0.f};
      #pragma unroll
      for (int m_ = 0; m_ < 2; ++m_)
        #pragma unroll
        for (int nt_ = 0; nt_ < NTI; ++nt_) acc[m_][nt_] = zz;
    }

    uint4 ab[3][C][2];

    // ---- software-pipelined K loop; own-peer wait deferred to first h chunk ----
    FETCH(0, 0);
    if constexpr (NC > 1) { if constexpr (CH == 1) WAITOWN; FETCH(1, 1); }
    if constexpr (NC > 2) { if constexpr (CH == 2) WAITOWN; FETCH(2, 2); }
    COMPUTE(0, 0);
    if constexpr (NC > 1) { if constexpr (NC > 3) { if constexpr (CH == 3) WAITOWN; FETCH(0, 3); } COMPUTE(1, 1); }
    if constexpr (NC > 2) { if constexpr (NC > 4) { if constexpr (CH == 4) WAITOWN; FETCH(1, 4); } COMPUTE(2, 2); }
    if constexpr (NC > 3) { if constexpr (NC > 5) { if constexpr (CH == 5) WAITOWN; FETCH(2, 5); } COMPUTE(0, 3); }
    if constexpr (NC > 4) COMPUTE(1, 4);
    if constexpr (NC > 5) COMPUTE(2, 5);

    // ---- D fragments -> z[gatecol][batch] in LDS (wave-disjoint columns) ----
    #pragma unroll
    for (int m_ = 0; m_ < 2; ++m_)
      #pragma unroll
      for (int nt_ = 0; nt_ < NTI; ++nt_)
        *(f32x4*)(z + (size_t)(nt_ * 16 + l15) * ZROW + w * 32 + m_ * 16 + (lane >> 4) * 4) =
            acc[m_][nt_];
    // (wave-internal LDS RAW: compiler-ordered lgkmcnt; columns are wave-local, no barrier)

    // ---- per-wave epilogue: gates, state, one coalesced 8B sc1 h store per lane ----
    if (epi) {
      float vi[4], vf[4], vg[4], vo[4];
      #pragma unroll
      for (int q = 0; q < 4; ++q) {
        const int nn = jg * 4 + q;
        vi[q] = z[(size_t)(0 * NJ + nn) * ZROW + be];
        vf[q] = z[(size_t)(1 * NJ + nn) * ZROW + be];
        vg[q] = z[(size_t)(2 * NJ + nn) * ZROW + be];
        vo[q] = z[(size_t)(3 * NJ + nn) * ZROW + be];
      }
      union { f16 h[4]; uint64_t u; } o;
      #pragma unroll
      for (int q = 0; q < 4; ++q) {
        const float ig = sigm(vi[q] + bias4[0][q]);
        const float fg = sigm(vf[q] + bias4[1][q]);
        const float gg = tanhf(vg[q] + bias4[2][q]);
        const float og = sigm(vo[q] + bias4[3][q]);
        cst[q] = fg * cst[q] + ig * gg;
        o.h[q] = (f16)(og * tanhf(cst[q]));
      }
      c_store8(ownH + (size_t)(t & (RING - 1)) * H * BATCH + (size_t)be * H + j0, o.u);
    }
    asm volatile("s_waitcnt vmcnt(0)" ::: "memory");      // per-wave drain (own stores only)
    if (lane == 0) u_store(&U[4 * bid + w], (unsigned)(t + 1));   // per-wave publish
  }
}
#undef FETCH
#undef COMPUTE
#undef WAITOWN

// ---------------- dense head ----------------
__device__ void dense_stage(const float* in, float* outb,
                            const float* __restrict__ w, const float* __restrict__ bias,
                            int din, int dout, bool relu) {
  for (int jc = threadIdx.x; jc < dout; jc += NT) {
    float s = bias[jc];
    for (int d = 0; d < din; ++d) s += in[d] * w[(size_t)d * dout + jc];
    outb[jc] = relu ? fmaxf(s, 0.f) : s;
  }
  __syncthreads();
}

constexpr size_t cmax(size_t a, size_t b) { return a > b ? a : b; }
constexpr size_t wlz(int NGC, int KPAD) {
  return (size_t)NGC * (KPAD + 8) * 2 + (size_t)NGC * 132 * 4;
}
static constexpr size_t SMEM_BYTES =
    cmax(cmax(wlz(32, 704), wlz(16, 1056)),
         cmax(cmax(wlz(32, 672), wlz(32, 512)), (size_t)4096));
static_assert(SMEM_BYTES <= 65536, "LDS");

// ---------------- fused cooperative kernel ----------------
template<int RING>
__global__ __launch_bounds__(NT, 1) void fused_kernel(KParams p) {
  using L = WS<RING>;
  cg::grid_group grid = cg::this_grid();
  __shared__ __attribute__((aligned(16))) char smem[SMEM_BYTES];

  char* ws = p.ws;
  unsigned* U = (unsigned*)(ws + L::BAR);
  const f16* zreg = (const f16*)(ws + L::ZERO);
  const int tid  = threadIdx.x;
  const int bid  = blockIdx.x;
  const int gtid = bid * NT + tid;
  const int gstr = NGRID * NT;

  // ---- phase 0a: prepack weights (f16, [blk][gatecol][k], K zero-padded to x32) ----
  prepack_layer(p.k1, p.r1, (f16*)(ws + L::PK1), 64,  640, 8, 704,  TB1, gtid, gstr);
  prepack_layer(p.k2, p.r2, (f16*)(ws + L::PK2), 640, 400, 4, 1056, TB2, gtid, gstr);
  prepack_layer(p.k3, p.r3, (f16*)(ws + L::PK3), 400, 256, 8, 672,  TB3, gtid, gstr);
  prepack_layer(p.k4, p.r4, (f16*)(ws + L::PK4), 256, 256, 8, 512,  TB4, gtid, gstr);

  // ---- phase 0b: x [128][512][64] f32 -> xT [512][128][64] f16 (batch-major) ----
  {
    f16* xT = (f16*)(ws + L::XT);
    const long total = (long)TSTEPS * BATCH * 8;
    for (long u = gtid; u < total; u += gstr) {
      const int  d8 = (int)(u & 7);
      const long r  = u >> 3;
      const int  b  = (int)(r & (BATCH - 1));
      const int  t  = (int)(r >> 7);
      const float* src = p.x + ((size_t)b * TSTEPS + t) * 64 + d8 * 8;
      const float4 v0 = *(const float4*)src;
      const float4 v1 = *(const float4*)(src + 4);
      h8v o;
      o[0] = (f16)v0.x; o[1] = (f16)v0.y; o[2] = (f16)v0.z; o[3] = (f16)v0.w;
      o[4] = (f16)v1.x; o[5] = (f16)v1.y; o[6] = (f16)v1.z; o[7] = (f16)v1.w;
      *(h8v*)(xT + ((size_t)t * BATCH + b) * 64 + d8 * 8) = o;
    }
  }

  grid.sync();   // publish packs/xT device-wide
  acq_fence();   // once per run: drop any stale ring lines from a prior launch

  // ---- phase 1: dataflow-pipelined 4-layer LSTM scan (MFMA, per-wave sync) ----
  constexpr int TRB2 = TB1, TRB3 = TB1 + TB2, TRB4 = TB1 + TB2 + TB3;
  if (bid >= TNB) {
    const int l = bid - TNB;
    if (l == 0)      control_role<TB1>(U, 0,    0);
    else if (l == 1) control_role<TB2>(U, TRB2, 1);
    else if (l == 2) control_role<TB3>(U, TRB3, 2);
    else             control_role<TB4>(U, TRB4, 3);
  } else if (bid < TRB2) {
    lstm_role< 64, 640, 8, 0, true , RING>(bid, bid, (const f16*)(ws + L::XT),
        (f16*)(ws + L::H1), (const f16*)(ws + L::PK1), p.b1, zreg, smem, U);
  } else if (bid < TRB3) {
    lstm_role<640, 400, 4, 1, false, RING>(bid - TRB2, bid, (const f16*)(ws + L::H1),
        (f16*)(ws + L::H2), (const f16*)(ws + L::PK2), p.b2, zreg, smem, U);
  } else if (bid < TRB4) {
    lstm_role<400, 256, 8, 2, false, RING>(bid - TRB3, bid, (const f16*)(ws + L::H2),
        (f16*)(ws + L::H3), (const f16*)(ws + L::PK3), p.b3, zreg, smem, U);
  } else {
    lstm_role<256, 256, 8, 3, false, RING>(bid - TRB4, bid, (const f16*)(ws + L::H3),
        (f16*)(ws + L::H4), (const f16*)(ws + L::PK4), p.b4, zreg, smem, U);
  }

  // ---- phase 2: dense head ----
  if (bid < BATCH) {
    {
      int cond = 1;
      if (tid < 4 * TB4) cond = ((int)u_load(&U[4 * (TRB4 + (tid >> 2)) + (tid & 3)]) >= TSTEPS);
      while (!__syncthreads_and(cond)) {
        if (!cond) cond = ((int)u_load(&U[4 * (TRB4 + (tid >> 2)) + (tid & 3)]) >= TSTEPS);
      }
    }
    const int b = bid;
    float* A = (float*)smem;
    float* B = (float*)smem + 512;
    const f16* h4 = (const f16*)(ws + L::H4)
                  + (size_t)((TSTEPS - 1) & (RING - 1)) * 256 * BATCH + (size_t)b * 256;
    for (int d = tid; d < 256; d += NT) {
      union { unsigned short u; f16 h; } cc;
      cc.u = c_load2(h4 + d);
      A[d] = (float)cc.h;
    }
    __syncthreads();
    dense_stage(A, B, p.wd1, p.bd1, 256, 512, true);
    dense_stage(B, A, p.wd2, p.bd2, 512, 256, true);
    dense_stage(A, B, p.wd3, p.bd3, 256, 128, true);
    dense_stage(B, A, p.wd4, p.bd4, 128, 64,  true);
    dense_stage(A, B, p.wd5, p.bd5, 64,  16,  true);
    dense_stage(B, A, p.wd6, p.bd6, 16,  3,   false);
    if (tid == 0) {
      float z0 = A[0], z1 = A[1], z2 = A[2];
      float m  = fmaxf(fmaxf(z0, z1), z2);
      float e0 = expf(z0 - m), e1 = expf(z1 - m), e2 = expf(z2 - m);
      float s  = e0 + e1 + e2;
      p.out[b * 3 + 0] = e0 / s;
      p.out[b * 3 + 1] = e1 / s;
      p.out[b * 3 + 2] = e2 / s;
    }
  }
}

// ---------------- launch ----------------
extern "C" void kernel_launch(void* const* d_in, const int* in_sizes, int n_in,
                              void* d_out, int out_size, void* d_ws, size_t ws_size,
                              hipStream_t stream) {
  (void)in_sizes; (void)n_in; (void)out_size;
  KParams prm;
  prm.x  = (const float*)d_in[0];
  prm.k1 = (const float*)d_in[1];  prm.r1 = (const float*)d_in[2];  prm.b1 = (const float*)d_in[3];
  prm.k2 = (const float*)d_in[4];  prm.r2 = (const float*)d_in[5];  prm.b2 = (const float*)d_in[6];
  prm.k3 = (const float*)d_in[7];  prm.r3 = (const float*)d_in[8];  prm.b3 = (const float*)d_in[9];
  prm.k4 = (const float*)d_in[10]; prm.r4 = (const float*)d_in[11]; prm.b4 = (const float*)d_in[12];
  prm.wd1 = (const float*)d_in[13]; prm.bd1 = (const float*)d_in[14];
  prm.wd2 = (const float*)d_in[15]; prm.bd2 = (const float*)d_in[16];
  prm.wd3 = (const float*)d_in[17]; prm.bd3 = (const float*)d_in[18];
  prm.wd4 = (const float*)d_in[19]; prm.bd4 = (const float*)d_in[20];
  prm.wd5 = (const float*)d_in[21]; prm.bd5 = (const float*)d_in[22];
  prm.wd6 = (const float*)d_in[23]; prm.bd6 = (const float*)d_in[24];
  prm.out = (float*)d_out;
  prm.ws  = (char*)d_ws;

  const bool big = ws_size >= WS<TSTEPS>::END;
  const size_t bar_off = big ? WS<TSTEPS>::BAR : WS<4>::BAR;
  // zero the sync area AND the h[-1] zero-region (contiguous)
  hipMemsetAsync((char*)d_ws + bar_off, 0, 8192 + 163840, stream);

  void* args[] = { &prm };
  if (big) {
    hipLaunchCooperativeKernel((void*)fused_kernel<TSTEPS>, dim3(NGRID), dim3(NT),
                               args, 0, stream);
  } else {
    hipLaunchCooperativeKernel((void*)fused_kernel<4>, dim3(NGRID), dim3(NT),
                               args, 0, stream);
  }
}